// Round 1
// baseline (3469.135 us; speedup 1.0000x reference)
//
#include <hip/hip_runtime.h>
#include <cstdint>

// ============================================================================
// ScaledCorticalColumn — fp32 correctness-first baseline.
//   h  = LN1(x) @ w_in + b_in
//   h += sparse_attn(h)            (top-k=64 masked softmax attention)
//   out = h + ( silu(LN2(h)@w_gate+b_gate) * (LN2(h)@w_up+b_up) ) @ w_down + b_down + ...
// All compute fp32 vector-ALU (no fp32 MFMA on CDNA4). Planned next: split-bf16
// MFMA GEMMs once tolerance headroom is measured.
// ============================================================================

#define DEV __device__ __forceinline__

constexpr int B_  = 2;
constexpr int N_  = 2048;
constexpr int D_  = 1024;
constexpr int H_  = 16;
constexpr int HD_ = 64;
constexpr int M_  = B_ * N_;          // 4096 rows
constexpr float EPS_ = 1e-5f;

DEV float4 ld4(const float* p) { return *reinterpret_cast<const float4*>(p); }
DEV void   st4(float* p, float4 v) { *reinterpret_cast<float4*>(p) = v; }

// ---------------------------------------------------------------------------
// LayerNorm: one block per row (D=1024, 256 threads x float4)
// ---------------------------------------------------------------------------
__global__ __launch_bounds__(256) void ln_kernel(const float* __restrict__ in,
                                                 const float* __restrict__ g,
                                                 const float* __restrict__ b,
                                                 float* __restrict__ out) {
  const int row = blockIdx.x;
  const int t = threadIdx.x;
  float4 v = ld4(in + (size_t)row * D_ + t * 4);
  float s  = v.x + v.y + v.z + v.w;
  float ss = v.x * v.x + v.y * v.y + v.z * v.z + v.w * v.w;
  #pragma unroll
  for (int o = 32; o; o >>= 1) { s += __shfl_down(s, o); ss += __shfl_down(ss, o); }
  __shared__ float rs[4], rss[4];
  const int wid = t >> 6, lane = t & 63;
  if (lane == 0) { rs[wid] = s; rss[wid] = ss; }
  __syncthreads();
  s  = rs[0] + rs[1] + rs[2] + rs[3];
  ss = rss[0] + rss[1] + rss[2] + rss[3];
  const float mean = s * (1.f / D_);
  const float var  = ss * (1.f / D_) - mean * mean;
  const float rstd = rsqrtf(var + EPS_);
  float4 gv = ld4(g + t * 4);
  float4 bv = ld4(b + t * 4);
  float4 o4;
  o4.x = (v.x - mean) * rstd * gv.x + bv.x;
  o4.y = (v.y - mean) * rstd * gv.y + bv.y;
  o4.z = (v.z - mean) * rstd * gv.z + bv.z;
  o4.w = (v.w - mean) * rstd * gv.w + bv.w;
  st4(out + (size_t)row * D_ + t * 4, o4);
}

// ---------------------------------------------------------------------------
// fp32 GEMM: C[M,N] = epi(A[M,K] @ W[K,N]).  128 x NT tile, BK=16, 256 thr,
// thread tile 8 x (NT/16). A staged transposed in LDS -> both frags ds_read_b128.
// ---------------------------------------------------------------------------
enum { EPI_NONE = 0, EPI_BIAS = 1, EPI_RES = 2, EPI_SILU = 3, EPI_MUL = 4 };

template <int NT, int EPI>
__global__ __launch_bounds__(256) void gemm_kernel(const float* __restrict__ A,
                                                   const float* __restrict__ W,
                                                   const float* __restrict__ bias,
                                                   const float* __restrict__ res,
                                                   float* __restrict__ C,
                                                   int M, int K, int N) {
  constexpr int BK = 16;
  constexpr int CT = NT / 16;              // cols per thread (8 or 4)
  __shared__ float As[BK][128 + 4];        // transposed: As[k][m]
  __shared__ float Bs[BK][NT + 4];
  const int tid = threadIdx.x;
  const int m0 = blockIdx.y * 128;
  const int n0 = blockIdx.x * NT;
  const int tx = tid & 15;                 // col group
  const int ty = tid >> 4;                 // row group 0..15

  float acc[8][CT];
  #pragma unroll
  for (int i = 0; i < 8; ++i)
    #pragma unroll
    for (int j = 0; j < CT; ++j) acc[i][j] = 0.f;

  const int ar = tid >> 2;                 // 0..63
  const int ac = (tid & 3) * 4;            // k offset 0,4,8,12
  const float* Ap0 = A + (size_t)(m0 + ar) * K + ac;
  const float* Ap1 = Ap0 + (size_t)64 * K;

  for (int k0 = 0; k0 < K; k0 += BK) {
    float4 a0 = ld4(Ap0 + k0);
    float4 a1 = ld4(Ap1 + k0);
    float4 b0, b1;
    if constexpr (NT == 128) {
      const int br = tid >> 5, bc = (tid & 31) * 4;
      b0 = ld4(W + (size_t)(k0 + br) * N + n0 + bc);
      b1 = ld4(W + (size_t)(k0 + br + 8) * N + n0 + bc);
    } else {
      const int br = tid >> 4, bc = (tid & 15) * 4;
      b0 = ld4(W + (size_t)(k0 + br) * N + n0 + bc);
      b1 = b0;
    }
    __syncthreads();                       // previous tile's compute done
    As[ac + 0][ar] = a0.x; As[ac + 1][ar] = a0.y;
    As[ac + 2][ar] = a0.z; As[ac + 3][ar] = a0.w;
    As[ac + 0][ar + 64] = a1.x; As[ac + 1][ar + 64] = a1.y;
    As[ac + 2][ar + 64] = a1.z; As[ac + 3][ar + 64] = a1.w;
    if constexpr (NT == 128) {
      const int br = tid >> 5, bc = (tid & 31) * 4;
      st4(&Bs[br][bc], b0);
      st4(&Bs[br + 8][bc], b1);
    } else {
      const int br = tid >> 4, bc = (tid & 15) * 4;
      st4(&Bs[br][bc], b0);
    }
    __syncthreads();
    #pragma unroll
    for (int kk = 0; kk < BK; ++kk) {
      float4 af0 = ld4(&As[kk][ty * 4]);
      float4 af1 = ld4(&As[kk][ty * 4 + 64]);
      float av[8] = {af0.x, af0.y, af0.z, af0.w, af1.x, af1.y, af1.z, af1.w};
      float bv[CT];
      float4 bf0 = ld4(&Bs[kk][tx * 4]);
      bv[0] = bf0.x; bv[1] = bf0.y; bv[2] = bf0.z; bv[3] = bf0.w;
      if constexpr (NT == 128) {
        float4 bf1 = ld4(&Bs[kk][tx * 4 + 64]);
        bv[4] = bf1.x; bv[5] = bf1.y; bv[6] = bf1.z; bv[7] = bf1.w;
      }
      #pragma unroll
      for (int i = 0; i < 8; ++i)
        #pragma unroll
        for (int j = 0; j < CT; ++j) acc[i][j] += av[i] * bv[j];
    }
  }

  // epilogue: rows {ty*4..+3} U {64+ty*4..+3}; cols tx*4 + g*64
  #pragma unroll
  for (int i = 0; i < 8; ++i) {
    const int m = m0 + ((i < 4) ? (ty * 4 + i) : (64 + ty * 4 + i - 4));
    #pragma unroll
    for (int g = 0; g < CT / 4; ++g) {
      const int n = n0 + tx * 4 + g * 64;
      float vals[4];
      #pragma unroll
      for (int j = 0; j < 4; ++j) vals[j] = acc[i][g * 4 + j];
      if constexpr (EPI != EPI_NONE) {
        float4 bq = ld4(bias + n);
        vals[0] += bq.x; vals[1] += bq.y; vals[2] += bq.z; vals[3] += bq.w;
      }
      if constexpr (EPI == EPI_RES) {
        float4 rq = ld4(res + (size_t)m * N + n);
        vals[0] += rq.x; vals[1] += rq.y; vals[2] += rq.z; vals[3] += rq.w;
      } else if constexpr (EPI == EPI_SILU) {
        #pragma unroll
        for (int j = 0; j < 4; ++j) vals[j] = vals[j] / (1.f + expf(-vals[j]));
      } else if constexpr (EPI == EPI_MUL) {
        float4 cq = ld4(C + (size_t)m * N + n);
        vals[0] *= cq.x; vals[1] *= cq.y; vals[2] *= cq.z; vals[3] *= cq.w;
      }
      float4 o4; o4.x = vals[0]; o4.y = vals[1]; o4.z = vals[2]; o4.w = vals[3];
      st4(C + (size_t)m * N + n, o4);
    }
  }
}

// ---------------------------------------------------------------------------
// Sparse attention, fused per (b, h, 4 q-rows):
//   phase 1: scores strip S[4][2048] in LDS (Q in regs, K chunks LDS-staged
//            with XOR-swizzled 16B chunks; d-split over the 4 waves)
//   phase 2: exact kth-largest per row via bitwise radix-select on
//            order-preserving uint keys held in registers (32/lane)
//   phase 3: masked softmax + sparse PV over only the selected (~64) columns
// ---------------------------------------------------------------------------
__global__ __launch_bounds__(256) void attn_kernel(const float* __restrict__ qm,
                                                   const float* __restrict__ km,
                                                   const float* __restrict__ vm,
                                                   float* __restrict__ ao,
                                                   const int* __restrict__ topk_p) {
  constexpr int QT = 4, CT = 128, NCH = N_ / CT;   // 16 chunks
  __shared__ float S[QT][N_];                      // 32 KB score strip
  __shared__ float Kc[CT][HD_];                    // 32 KB K chunk (swizzled)
  __shared__ float Pt[4][QT][CT];                  // 8 KB partial sums (d-split)

  const int tid = threadIdx.x;
  const int bid = blockIdx.x;
  const int qt = bid & (N_ / QT - 1);              // 0..511
  const int hh = (bid >> 9) & (H_ - 1);
  const int bb = bid >> 13;
  const int q0 = qt * QT;
  const size_t baseKV = (size_t)bb * N_ * D_ + (size_t)hh * HD_;
  const int tc = tid & 63;                         // col within half-chunk
  const int th = tid >> 6;                         // wave id = d-quadrant
  const float scale = 0.125f;                      // HD^-0.5

  // Q rows into registers (wave-uniform loads; 16 d's per wave = this wave's slice)
  float4 qr[QT][4];
  #pragma unroll
  for (int r = 0; r < QT; ++r)
    #pragma unroll
    for (int dq = 0; dq < 4; ++dq) {
      float4 t = ld4(qm + baseKV + (size_t)(q0 + r) * D_ + th * 16 + dq * 4);
      t.x *= scale; t.y *= scale; t.z *= scale; t.w *= scale;
      qr[r][dq] = t;
    }

  for (int cb = 0; cb < NCH; ++cb) {
    // stage K chunk: issue all global loads before the barrier
    float4 kst[8];
    #pragma unroll
    for (int it = 0; it < 8; ++it) {
      const int c = it * 16 + (tid >> 4);
      kst[it] = ld4(km + baseKV + (size_t)(cb * CT + c) * D_ + (tid & 15) * 4);
    }
    __syncthreads();                               // prev chunk fully consumed
    #pragma unroll
    for (int it = 0; it < 8; ++it) {
      const int c = it * 16 + (tid >> 4);
      const int chk = (tid & 15) ^ (c & 15);       // XOR-swizzle 16B chunks
      st4(&Kc[c][chk * 4], kst[it]);
    }
    __syncthreads();

    // compute: this thread covers cols {tc, tc+64}, d in [th*16, th*16+16)
    float pa[QT][2];
    #pragma unroll
    for (int r = 0; r < QT; ++r) { pa[r][0] = 0.f; pa[r][1] = 0.f; }
    #pragma unroll
    for (int dq = 0; dq < 4; ++dq) {
      const int ch = th * 4 + dq;
      float4 k0 = ld4(&Kc[tc][(ch ^ (tc & 15)) * 4]);
      float4 k1 = ld4(&Kc[tc + 64][(ch ^ (tc & 15)) * 4]);
      #pragma unroll
      for (int r = 0; r < QT; ++r) {
        float4 qv = qr[r][dq];
        pa[r][0] += qv.x * k0.x + qv.y * k0.y + qv.z * k0.z + qv.w * k0.w;
        pa[r][1] += qv.x * k1.x + qv.y * k1.y + qv.z * k1.z + qv.w * k1.w;
      }
    }
    #pragma unroll
    for (int r = 0; r < QT; ++r) {
      Pt[th][r][tc]      = pa[r][0];
      Pt[th][r][tc + 64] = pa[r][1];
    }
    __syncthreads();
    // combine the 4 d-partials -> S
    {
      const int rr = tid >> 6, cc = tid & 63;
      S[rr][cb * CT + cc] = Pt[0][rr][cc] + Pt[1][rr][cc] + Pt[2][rr][cc] + Pt[3][rr][cc];
      S[rr][cb * CT + cc + 64] =
          Pt[0][rr][cc + 64] + Pt[1][rr][cc + 64] + Pt[2][rr][cc + 64] + Pt[3][rr][cc + 64];
    }
  }
  __syncthreads();

  // ---- phase 2: per row (wave w), exact kth largest of 2048 scores ----
  int topk = *topk_p;
  if (topk > N_) topk = N_;
  const int w = tid >> 6, lane = tid & 63;

  unsigned key[32];
  float smax = -3.4e38f;
  #pragma unroll
  for (int j = 0; j < 32; ++j) {
    float sv = S[w][lane + 64 * j];
    smax = fmaxf(smax, sv);
    unsigned u = __float_as_uint(sv);
    key[j] = u ^ ((unsigned)((int)u >> 31) | 0x80000000u);  // order-preserving map
  }
  #pragma unroll
  for (int o = 32; o; o >>= 1) smax = fmaxf(smax, __shfl_xor(smax, o));

  unsigned thr = 0u;
  for (int bit = 31; bit >= 0; --bit) {            // radix-select (keys in regs)
    const unsigned cand = thr | (1u << bit);
    int cnt = 0;
    #pragma unroll
    for (int j = 0; j < 32; ++j) cnt += (key[j] >= cand) ? 1 : 0;
    #pragma unroll
    for (int o = 32; o; o >>= 1) cnt += __shfl_xor(cnt, o);
    if (cnt >= topk) thr = cand;
  }
  const float thrF =
      __uint_as_float((thr & 0x80000000u) ? (thr ^ 0x80000000u) : ~thr);

  // ---- phase 3: masked softmax + sparse PV (only selected columns) ----
  float outv = 0.f, wsum = 0.f;
  const float* Vb = vm + baseKV;
  for (int j = 0; j < 32; ++j) {
    const float sv = S[w][lane + 64 * j];
    unsigned long long msk = __ballot(sv >= thrF);
    while (msk) {
      const int src = __ffsll(msk) - 1;
      msk &= msk - 1;
      const float svb = __shfl(sv, src);           // wave-uniform score
      const float wgt = expf(svb - smax);          // one exp per selected col
      wsum += wgt;
      outv += wgt * Vb[(size_t)(j * 64 + src) * D_ + lane];
    }
  }
  ao[((size_t)bb * N_ + q0 + w) * D_ + hh * HD_ + lane] = outv / wsum;
}

// ---------------------------------------------------------------------------
// Orchestration.  ws layout (floats, SZ = 4096*1024 = 4M):
//   [0,SZ)   xn   (LN1 out)  -> reused as attn output ao
//   [SZ,2SZ) hp   (pre-attn h, then h after residual, in place)
//   [2SZ,3SZ) q   -> reused as ff_in (LN2 out)
//   [3SZ,4SZ) k \ 
//   [4SZ,5SZ) v  +-> [3SZ,7SZ) ff1 (gate*up, 4096x4096) after attention
//   total 7*SZ floats = 112 MB of d_ws
// ---------------------------------------------------------------------------
extern "C" void kernel_launch(void* const* d_in, const int* in_sizes, int n_in,
                              void* d_out, int out_size, void* d_ws, size_t ws_size,
                              hipStream_t stream) {
  const float* x      = (const float*)d_in[0];
  const float* ln1_g  = (const float*)d_in[1];
  const float* ln1_b  = (const float*)d_in[2];
  const float* w_in   = (const float*)d_in[3];
  const float* b_in   = (const float*)d_in[4];
  const float* wq     = (const float*)d_in[5];
  const float* wk     = (const float*)d_in[6];
  const float* wv     = (const float*)d_in[7];
  const float* wo     = (const float*)d_in[8];
  const float* bo     = (const float*)d_in[9];
  const float* ln2_g  = (const float*)d_in[10];
  const float* ln2_b  = (const float*)d_in[11];
  const float* w_up   = (const float*)d_in[12];
  const float* b_up   = (const float*)d_in[13];
  const float* w_gate = (const float*)d_in[14];
  const float* b_gate = (const float*)d_in[15];
  const float* w_down = (const float*)d_in[16];
  const float* b_down = (const float*)d_in[17];
  const int*   topk   = (const int*)d_in[18];
  float* out = (float*)d_out;

  float* ws = (float*)d_ws;
  const size_t SZ = (size_t)M_ * D_;
  float* xn  = ws;               // later: ao
  float* hp  = ws + SZ;          // h (in-place residual)
  float* qb  = ws + 2 * SZ;      // later: ff_in
  float* kb  = ws + 3 * SZ;
  float* vb  = ws + 4 * SZ;
  float* ff1 = ws + 3 * SZ;      // 16M floats, reuses kb/vb after attention

  const dim3 blk(256);
  const dim3 g1024(D_ / 64, M_ / 128);        // N=1024 GEMMs: 16x32 = 512 blocks
  const dim3 g4096(4 * D_ / 128, M_ / 128);   // N=4096 GEMMs: 32x32 = 1024 blocks

  // 1) xn = LN1(x)
  ln_kernel<<<M_, blk, 0, stream>>>(x, ln1_g, ln1_b, xn);
  // 2) hp = xn @ w_in + b_in
  gemm_kernel<64, EPI_BIAS><<<g1024, blk, 0, stream>>>(xn, w_in, b_in, nullptr, hp, M_, D_, D_);
  // 3-5) q,k,v = hp @ {wq,wk,wv}
  gemm_kernel<64, EPI_NONE><<<g1024, blk, 0, stream>>>(hp, wq, nullptr, nullptr, qb, M_, D_, D_);
  gemm_kernel<64, EPI_NONE><<<g1024, blk, 0, stream>>>(hp, wk, nullptr, nullptr, kb, M_, D_, D_);
  gemm_kernel<64, EPI_NONE><<<g1024, blk, 0, stream>>>(hp, wv, nullptr, nullptr, vb, M_, D_, D_);
  // 6) ao = sparse_attention core (into xn)
  attn_kernel<<<B_ * H_ * (N_ / 4), blk, 0, stream>>>(qb, kb, vb, xn, topk);
  // 7) h = hp + ao @ wo + bo   (in place into hp)
  gemm_kernel<64, EPI_RES><<<g1024, blk, 0, stream>>>(xn, wo, bo, hp, hp, M_, D_, D_);
  // 8) ff_in = LN2(h)  (into qb)
  ln_kernel<<<M_, blk, 0, stream>>>(hp, ln2_g, ln2_b, qb);
  // 9) ff1 = silu(ff_in @ w_gate + b_gate)
  gemm_kernel<128, EPI_SILU><<<g4096, blk, 0, stream>>>(qb, w_gate, b_gate, nullptr, ff1, M_, D_, 4 * D_);
  // 10) ff1 *= (ff_in @ w_up + b_up)
  gemm_kernel<128, EPI_MUL><<<g4096, blk, 0, stream>>>(qb, w_up, b_up, nullptr, ff1, M_, D_, 4 * D_);
  // 11) out = h + ff1 @ w_down + b_down
  gemm_kernel<64, EPI_RES><<<g1024, blk, 0, stream>>>(ff1, w_down, b_down, hp, out, M_, 4 * D_, D_);
}

// Round 2
// 2685.596 us; speedup vs baseline: 1.2918x; 1.2918x over previous
//
#include <hip/hip_runtime.h>
#include <cstdint>

// ============================================================================
// ScaledCorticalColumn — R2: attention restructured (scores-in-regs, SALU radix
// count, compacted parallel V-gather, XCD-local K/V). GEMMs unchanged from R1
// for a clean A/B; split-bf16 MFMA GEMMs planned next round.
// ============================================================================

#define DEV __device__ __forceinline__

constexpr int B_  = 2;
constexpr int N_  = 2048;
constexpr int D_  = 1024;
constexpr int H_  = 16;
constexpr int HD_ = 64;
constexpr int M_  = B_ * N_;          // 4096 rows
constexpr float EPS_ = 1e-5f;

DEV float4 ld4(const float* p) { return *reinterpret_cast<const float4*>(p); }
DEV void   st4(float* p, float4 v) { *reinterpret_cast<float4*>(p) = v; }

// order-preserving float<->uint key map (monotone bijection, tie-exact)
DEV unsigned fkey(float f) {
  unsigned u = __float_as_uint(f);
  return u ^ ((unsigned)((int)u >> 31) | 0x80000000u);
}
DEV float fval(unsigned k) {
  unsigned u = (k & 0x80000000u) ? (k ^ 0x80000000u) : ~k;
  return __uint_as_float(u);
}

// ---------------------------------------------------------------------------
// LayerNorm: one block per row (D=1024, 256 threads x float4)
// ---------------------------------------------------------------------------
__global__ __launch_bounds__(256) void ln_kernel(const float* __restrict__ in,
                                                 const float* __restrict__ g,
                                                 const float* __restrict__ b,
                                                 float* __restrict__ out) {
  const int row = blockIdx.x;
  const int t = threadIdx.x;
  float4 v = ld4(in + (size_t)row * D_ + t * 4);
  float s  = v.x + v.y + v.z + v.w;
  float ss = v.x * v.x + v.y * v.y + v.z * v.z + v.w * v.w;
  #pragma unroll
  for (int o = 32; o; o >>= 1) { s += __shfl_down(s, o); ss += __shfl_down(ss, o); }
  __shared__ float rs[4], rss[4];
  const int wid = t >> 6, lane = t & 63;
  if (lane == 0) { rs[wid] = s; rss[wid] = ss; }
  __syncthreads();
  s  = rs[0] + rs[1] + rs[2] + rs[3];
  ss = rss[0] + rss[1] + rss[2] + rss[3];
  const float mean = s * (1.f / D_);
  const float var  = ss * (1.f / D_) - mean * mean;
  const float rstd = rsqrtf(var + EPS_);
  float4 gv = ld4(g + t * 4);
  float4 bv = ld4(b + t * 4);
  float4 o4;
  o4.x = (v.x - mean) * rstd * gv.x + bv.x;
  o4.y = (v.y - mean) * rstd * gv.y + bv.y;
  o4.z = (v.z - mean) * rstd * gv.z + bv.z;
  o4.w = (v.w - mean) * rstd * gv.w + bv.w;
  st4(out + (size_t)row * D_ + t * 4, o4);
}

// ---------------------------------------------------------------------------
// fp32 GEMM (unchanged from R1)
// ---------------------------------------------------------------------------
enum { EPI_NONE = 0, EPI_BIAS = 1, EPI_RES = 2, EPI_SILU = 3, EPI_MUL = 4 };

template <int NT, int EPI>
__global__ __launch_bounds__(256) void gemm_kernel(const float* __restrict__ A,
                                                   const float* __restrict__ W,
                                                   const float* __restrict__ bias,
                                                   const float* __restrict__ res,
                                                   float* __restrict__ C,
                                                   int M, int K, int N) {
  constexpr int BK = 16;
  constexpr int CT = NT / 16;
  __shared__ float As[BK][128 + 4];
  __shared__ float Bs[BK][NT + 4];
  const int tid = threadIdx.x;
  const int m0 = blockIdx.y * 128;
  const int n0 = blockIdx.x * NT;
  const int tx = tid & 15;
  const int ty = tid >> 4;

  float acc[8][CT];
  #pragma unroll
  for (int i = 0; i < 8; ++i)
    #pragma unroll
    for (int j = 0; j < CT; ++j) acc[i][j] = 0.f;

  const int ar = tid >> 2;
  const int ac = (tid & 3) * 4;
  const float* Ap0 = A + (size_t)(m0 + ar) * K + ac;
  const float* Ap1 = Ap0 + (size_t)64 * K;

  for (int k0 = 0; k0 < K; k0 += BK) {
    float4 a0 = ld4(Ap0 + k0);
    float4 a1 = ld4(Ap1 + k0);
    float4 b0, b1;
    if constexpr (NT == 128) {
      const int br = tid >> 5, bc = (tid & 31) * 4;
      b0 = ld4(W + (size_t)(k0 + br) * N + n0 + bc);
      b1 = ld4(W + (size_t)(k0 + br + 8) * N + n0 + bc);
    } else {
      const int br = tid >> 4, bc = (tid & 15) * 4;
      b0 = ld4(W + (size_t)(k0 + br) * N + n0 + bc);
      b1 = b0;
    }
    __syncthreads();
    As[ac + 0][ar] = a0.x; As[ac + 1][ar] = a0.y;
    As[ac + 2][ar] = a0.z; As[ac + 3][ar] = a0.w;
    As[ac + 0][ar + 64] = a1.x; As[ac + 1][ar + 64] = a1.y;
    As[ac + 2][ar + 64] = a1.z; As[ac + 3][ar + 64] = a1.w;
    if constexpr (NT == 128) {
      const int br = tid >> 5, bc = (tid & 31) * 4;
      st4(&Bs[br][bc], b0);
      st4(&Bs[br + 8][bc], b1);
    } else {
      const int br = tid >> 4, bc = (tid & 15) * 4;
      st4(&Bs[br][bc], b0);
    }
    __syncthreads();
    #pragma unroll
    for (int kk = 0; kk < BK; ++kk) {
      float4 af0 = ld4(&As[kk][ty * 4]);
      float4 af1 = ld4(&As[kk][ty * 4 + 64]);
      float av[8] = {af0.x, af0.y, af0.z, af0.w, af1.x, af1.y, af1.z, af1.w};
      float bv[CT];
      float4 bf0 = ld4(&Bs[kk][tx * 4]);
      bv[0] = bf0.x; bv[1] = bf0.y; bv[2] = bf0.z; bv[3] = bf0.w;
      if constexpr (NT == 128) {
        float4 bf1 = ld4(&Bs[kk][tx * 4 + 64]);
        bv[4] = bf1.x; bv[5] = bf1.y; bv[6] = bf1.z; bv[7] = bf1.w;
      }
      #pragma unroll
      for (int i = 0; i < 8; ++i)
        #pragma unroll
        for (int j = 0; j < CT; ++j) acc[i][j] += av[i] * bv[j];
    }
  }

  #pragma unroll
  for (int i = 0; i < 8; ++i) {
    const int m = m0 + ((i < 4) ? (ty * 4 + i) : (64 + ty * 4 + i - 4));
    #pragma unroll
    for (int g = 0; g < CT / 4; ++g) {
      const int n = n0 + tx * 4 + g * 64;
      float vals[4];
      #pragma unroll
      for (int j = 0; j < 4; ++j) vals[j] = acc[i][g * 4 + j];
      if constexpr (EPI != EPI_NONE) {
        float4 bq = ld4(bias + n);
        vals[0] += bq.x; vals[1] += bq.y; vals[2] += bq.z; vals[3] += bq.w;
      }
      if constexpr (EPI == EPI_RES) {
        float4 rq = ld4(res + (size_t)m * N + n);
        vals[0] += rq.x; vals[1] += rq.y; vals[2] += rq.z; vals[3] += rq.w;
      } else if constexpr (EPI == EPI_SILU) {
        #pragma unroll
        for (int j = 0; j < 4; ++j) vals[j] = vals[j] / (1.f + expf(-vals[j]));
      } else if constexpr (EPI == EPI_MUL) {
        float4 cq = ld4(C + (size_t)m * N + n);
        vals[0] *= cq.x; vals[1] *= cq.y; vals[2] *= cq.z; vals[3] *= cq.w;
      }
      float4 o4; o4.x = vals[0]; o4.y = vals[1]; o4.z = vals[2]; o4.w = vals[3];
      st4(C + (size_t)m * N + n, o4);
    }
  }
}

// ---------------------------------------------------------------------------
// Sparse attention v2, per block: (b, h, 4 q-rows), 256 threads = 4 waves.
//   phase 1: QK^T, d-split over waves; scores land directly in registers
//            (wave = row, lane l holds cols l+64j, j=0..31). No S strip.
//   phase 2: exact kth-largest via radix-select on order-preserving keys;
//            count via wave-uniform __ballot + popcount (SALU, no butterfly).
//   phase 3: compact (idx, weight) to LDS (aliases dead Pt), then 16-wide
//            batched independent V loads (parallel gather, L2-resident via
//            XCD-chunked block swizzle).
// LDS: Kc 32 KB + Pt 8 KB = 40 KB -> 4 blocks/CU.
// ---------------------------------------------------------------------------
__global__ __launch_bounds__(256) void attn_kernel(const float* __restrict__ qm,
                                                   const float* __restrict__ km,
                                                   const float* __restrict__ vm,
                                                   float* __restrict__ ao,
                                                   const int* __restrict__ topk_p) {
  constexpr int QT = 4, CT = 128, NCH = N_ / CT;   // 16 chunks
  constexpr int NJ = 2 * NCH;                      // 32 cols per lane
  __shared__ float Kc[CT][HD_];                    // 32 KB (XOR-swizzled rows)
  __shared__ float Pt[4][QT][CT];                  // 8 KB; aliased in phase 3
  int*   selIdx = (int*)&Pt[0][0][0];              // [4][128] ints   (4 KB)
  float* selW   = (float*)&Pt[2][0][0];            // [4][128] floats (4 KB)

  const int tid = threadIdx.x;
  // XCD-chunked bijective swizzle: 16384 blocks = 8 XCDs x 2048.
  // Co-resident blocks on an XCD share one (b,h)'s K/V (1 MB) -> L2-resident.
  const int bid = ((blockIdx.x & 7) << 11) | (blockIdx.x >> 3);
  const int qt = bid & (N_ / QT - 1);              // 0..511
  const int hh = (bid >> 9) & (H_ - 1);
  const int bb = bid >> 13;
  const int q0 = qt * QT;
  const size_t baseKV = (size_t)bb * N_ * D_ + (size_t)hh * HD_;
  const int lane = tid & 63;                       // col (phase1/2/3) / d (gather)
  const int w = tid >> 6;                          // wave id = d-quadrant = row
  const float scale = 0.125f;                      // HD^-0.5

  // Q rows into registers: this wave's d-slice [w*16, w*16+16) for all 4 rows
  float4 qr[QT][4];
  #pragma unroll
  for (int r = 0; r < QT; ++r)
    #pragma unroll
    for (int dq = 0; dq < 4; ++dq) {
      float4 t = ld4(qm + baseKV + (size_t)(q0 + r) * D_ + w * 16 + dq * 4);
      t.x *= scale; t.y *= scale; t.z *= scale; t.w *= scale;
      qr[r][dq] = t;
    }

  // ---- phase 1: scores -> key[NJ] registers ----
  unsigned key[NJ];
  for (int cb = 0; cb < NCH; ++cb) {
    float4 kst[8];
    #pragma unroll
    for (int it = 0; it < 8; ++it) {
      const int c = it * 16 + (tid >> 4);
      kst[it] = ld4(km + baseKV + (size_t)(cb * CT + c) * D_ + (tid & 15) * 4);
    }
    __syncthreads();                 // prev Kc reads + prev Pt combine done
    #pragma unroll
    for (int it = 0; it < 8; ++it) {
      const int c = it * 16 + (tid >> 4);
      const int chk = (tid & 15) ^ (c & 15);       // XOR-swizzle 16B chunks
      st4(&Kc[c][chk * 4], kst[it]);
    }
    __syncthreads();

    float pa[QT][2];
    #pragma unroll
    for (int r = 0; r < QT; ++r) { pa[r][0] = 0.f; pa[r][1] = 0.f; }
    #pragma unroll
    for (int dq = 0; dq < 4; ++dq) {
      const int ch = w * 4 + dq;
      float4 k0 = ld4(&Kc[lane][(ch ^ (lane & 15)) * 4]);
      float4 k1 = ld4(&Kc[lane + 64][(ch ^ (lane & 15)) * 4]);
      #pragma unroll
      for (int r = 0; r < QT; ++r) {
        float4 qv = qr[r][dq];
        pa[r][0] += qv.x * k0.x + qv.y * k0.y + qv.z * k0.z + qv.w * k0.w;
        pa[r][1] += qv.x * k1.x + qv.y * k1.y + qv.z * k1.z + qv.w * k1.w;
      }
    }
    #pragma unroll
    for (int r = 0; r < QT; ++r) {
      Pt[w][r][lane]      = pa[r][0];
      Pt[w][r][lane + 64] = pa[r][1];
    }
    __syncthreads();
    // combine d-quadrants; this thread keeps row w, cols {128cb+lane, +64}
    {
      float s0 = Pt[0][w][lane] + Pt[1][w][lane] + Pt[2][w][lane] + Pt[3][w][lane];
      float s1 = Pt[0][w][lane + 64] + Pt[1][w][lane + 64] +
                 Pt[2][w][lane + 64] + Pt[3][w][lane + 64];
      key[2 * cb]     = fkey(s0);     // col = (2cb)*64 + lane
      key[2 * cb + 1] = fkey(s1);     // col = (2cb+1)*64 + lane
    }
  }

  // ---- phase 2: row max + exact kth-largest key (radix-select) ----
  int topk = *topk_p;
  if (topk > N_) topk = N_;

  unsigned kmax = 0;
  #pragma unroll
  for (int j = 0; j < NJ; ++j) kmax = (key[j] > kmax) ? key[j] : kmax;
  #pragma unroll
  for (int o = 32; o; o >>= 1) {
    unsigned t = __shfl_xor(kmax, o);
    kmax = (t > kmax) ? t : kmax;
  }
  const float smax = fval(kmax);

  unsigned thr = 0u;
  if (topk < N_) {
    for (int bit = 31; bit >= 0; --bit) {
      const unsigned cand = thr | (1u << bit);
      int c = 0;
      #pragma unroll
      for (int j = 0; j < NJ; ++j)
        c += __popcll(__ballot(key[j] >= cand));   // wave-uniform count
      if (c >= topk) thr = cand;
    }
  }

  // ---- phase 3: compact selected (idx, weight), then parallel V gather ----
  __syncthreads();                                 // Pt dead -> sel alias safe
  int base = 0;
  float wpart = 0.f;
  #pragma unroll
  for (int j = 0; j < NJ; ++j) {
    const bool sel = key[j] >= thr;                // tie-exact vs kth value
    const unsigned long long m = __ballot(sel);
    if (sel) {
      const int pos = base + (int)__popcll(m & ((1ull << lane) - 1ull));
      if (pos < 128) {
        const float wgt = expf(fval(key[j]) - smax);
        selIdx[w * 128 + pos] = j * 64 + lane;
        selW[w * 128 + pos] = wgt;
        wpart += wgt;
      }
    }
    base += (int)__popcll(m);
  }
  int cnt = (base > 128) ? 128 : base;
  float wsum = wpart;
  #pragma unroll
  for (int o = 32; o; o >>= 1) wsum += __shfl_xor(wsum, o);

  // gather: wave w handles row w; lane = d; 16-wide independent load batches
  const float* Vb = vm + baseKV;
  float outv = 0.f;
  int i = 0;
  for (; i + 16 <= cnt; i += 16) {
    int ix[16]; float wv[16], vv[16];
    #pragma unroll
    for (int t = 0; t < 16; ++t) {
      ix[t] = selIdx[w * 128 + i + t];             // LDS broadcast
      wv[t] = selW[w * 128 + i + t];
    }
    #pragma unroll
    for (int t = 0; t < 16; ++t) vv[t] = Vb[(size_t)ix[t] * D_ + lane];
    #pragma unroll
    for (int t = 0; t < 16; ++t) outv += wv[t] * vv[t];
  }
  for (; i < cnt; ++i)
    outv += selW[w * 128 + i] * Vb[(size_t)selIdx[w * 128 + i] * D_ + lane];

  ao[((size_t)bb * N_ + q0 + w) * D_ + hh * HD_ + lane] = outv / wsum;
}

// ---------------------------------------------------------------------------
// Orchestration (unchanged layout).  ws: 7 * 4M floats = 112 MB.
// ---------------------------------------------------------------------------
extern "C" void kernel_launch(void* const* d_in, const int* in_sizes, int n_in,
                              void* d_out, int out_size, void* d_ws, size_t ws_size,
                              hipStream_t stream) {
  const float* x      = (const float*)d_in[0];
  const float* ln1_g  = (const float*)d_in[1];
  const float* ln1_b  = (const float*)d_in[2];
  const float* w_in   = (const float*)d_in[3];
  const float* b_in   = (const float*)d_in[4];
  const float* wq     = (const float*)d_in[5];
  const float* wk     = (const float*)d_in[6];
  const float* wv     = (const float*)d_in[7];
  const float* wo     = (const float*)d_in[8];
  const float* bo     = (const float*)d_in[9];
  const float* ln2_g  = (const float*)d_in[10];
  const float* ln2_b  = (const float*)d_in[11];
  const float* w_up   = (const float*)d_in[12];
  const float* b_up   = (const float*)d_in[13];
  const float* w_gate = (const float*)d_in[14];
  const float* b_gate = (const float*)d_in[15];
  const float* w_down = (const float*)d_in[16];
  const float* b_down = (const float*)d_in[17];
  const int*   topk   = (const int*)d_in[18];
  float* out = (float*)d_out;

  float* ws = (float*)d_ws;
  const size_t SZ = (size_t)M_ * D_;
  float* xn  = ws;               // later: attn output
  float* hp  = ws + SZ;          // h (in-place residual)
  float* qb  = ws + 2 * SZ;      // later: ff_in
  float* kb  = ws + 3 * SZ;
  float* vb  = ws + 4 * SZ;
  float* ff1 = ws + 3 * SZ;      // reuses kb/vb after attention

  const dim3 blk(256);
  const dim3 g1024(D_ / 64, M_ / 128);
  const dim3 g4096(4 * D_ / 128, M_ / 128);

  ln_kernel<<<M_, blk, 0, stream>>>(x, ln1_g, ln1_b, xn);
  gemm_kernel<64, EPI_BIAS><<<g1024, blk, 0, stream>>>(xn, w_in, b_in, nullptr, hp, M_, D_, D_);
  gemm_kernel<64, EPI_NONE><<<g1024, blk, 0, stream>>>(hp, wq, nullptr, nullptr, qb, M_, D_, D_);
  gemm_kernel<64, EPI_NONE><<<g1024, blk, 0, stream>>>(hp, wk, nullptr, nullptr, kb, M_, D_, D_);
  gemm_kernel<64, EPI_NONE><<<g1024, blk, 0, stream>>>(hp, wv, nullptr, nullptr, vb, M_, D_, D_);
  attn_kernel<<<B_ * H_ * (N_ / 4), blk, 0, stream>>>(qb, kb, vb, xn, topk);
  gemm_kernel<64, EPI_RES><<<g1024, blk, 0, stream>>>(xn, wo, bo, hp, hp, M_, D_, D_);
  ln_kernel<<<M_, blk, 0, stream>>>(hp, ln2_g, ln2_b, qb);
  gemm_kernel<128, EPI_SILU><<<g4096, blk, 0, stream>>>(qb, w_gate, b_gate, nullptr, ff1, M_, D_, 4 * D_);
  gemm_kernel<128, EPI_MUL><<<g4096, blk, 0, stream>>>(qb, w_up, b_up, nullptr, ff1, M_, D_, 4 * D_);
  gemm_kernel<64, EPI_RES><<<g1024, blk, 0, stream>>>(ff1, w_down, b_down, hp, out, M_, 4 * D_, D_);
}

// Round 4
// 1516.227 us; speedup vs baseline: 2.2880x; 1.7712x over previous
//
#include <hip/hip_runtime.h>
#include <cstdint>

// ============================================================================
// ScaledCorticalColumn — R4 (= R3 math, ws-safe layout): split-bf16 (hi/lo,
// 3-product) MFMA GEMMs. Weights transpose-converted per launch to [N][K]
// bf16 hi/lo planes; activations produced as hi/lo pairs by producer
// epilogues. Attention unchanged from R2 except pair output. FFN runs in two
// N-chunks (split-K down-proj accumulating in-place into d_out) so the whole
// workspace extent is 100 MB (< proven-safe 112 MB).
// ============================================================================

#define DEV __device__ __forceinline__

constexpr int B_  = 2;
constexpr int N_  = 2048;
constexpr int D_  = 1024;
constexpr int H_  = 16;
constexpr int HD_ = 64;
constexpr int M_  = B_ * N_;          // 4096 rows
constexpr float EPS_ = 1e-5f;

using short8 = __attribute__((ext_vector_type(8))) short;
using f32x4  = __attribute__((ext_vector_type(4))) float;

DEV float4 ld4(const float* p) { return *reinterpret_cast<const float4*>(p); }
DEV void   st4(float* p, float4 v) { *reinterpret_cast<float4*>(p) = v; }

// bf16 round-to-nearest-even split helpers
DEV unsigned short bf16r(float x) {
  unsigned u = __float_as_uint(x);
  u += 0x7fffu + ((u >> 16) & 1u);
  return (unsigned short)(u >> 16);
}
DEV float bf2f(unsigned short h) { return __uint_as_float(((unsigned)h) << 16); }

// order-preserving float<->uint key map (monotone bijection, tie-exact)
DEV unsigned fkey(float f) {
  unsigned u = __float_as_uint(f);
  return u ^ ((unsigned)((int)u >> 31) | 0x80000000u);
}
DEV float fval(unsigned k) {
  unsigned u = (k & 0x80000000u) ? (k ^ 0x80000000u) : ~k;
  return __uint_as_float(u);
}

// ---------------------------------------------------------------------------
// Weight transpose-convert: W f32 [K][N] -> Thi/Tlo bf16 [N][K]. 32x32 tiles.
// grid = (N/32, K/32)
// ---------------------------------------------------------------------------
__global__ __launch_bounds__(256) void wconv_kernel(const float* __restrict__ W,
                                                    unsigned short* __restrict__ Thi,
                                                    unsigned short* __restrict__ Tlo,
                                                    int K, int N) {
  __shared__ float t[32][33];
  const int k0 = blockIdx.y * 32, n0 = blockIdx.x * 32;
  const int tid = threadIdx.x;
  const int r = tid >> 3, c4 = (tid & 7) * 4;
  float4 v = ld4(W + (size_t)(k0 + r) * N + n0 + c4);
  t[r][c4 + 0] = v.x; t[r][c4 + 1] = v.y; t[r][c4 + 2] = v.z; t[r][c4 + 3] = v.w;
  __syncthreads();
  const int n = tid >> 3, kc = (tid & 7) * 4;
  ushort4 hv, lv;
  {
    float x0 = t[kc + 0][n], x1 = t[kc + 1][n], x2 = t[kc + 2][n], x3 = t[kc + 3][n];
    hv.x = bf16r(x0); lv.x = bf16r(x0 - bf2f(hv.x));
    hv.y = bf16r(x1); lv.y = bf16r(x1 - bf2f(hv.y));
    hv.z = bf16r(x2); lv.z = bf16r(x2 - bf2f(hv.z));
    hv.w = bf16r(x3); lv.w = bf16r(x3 - bf2f(hv.w));
  }
  *reinterpret_cast<ushort4*>(&Thi[(size_t)(n0 + n) * K + k0 + kc]) = hv;
  *reinterpret_cast<ushort4*>(&Tlo[(size_t)(n0 + n) * K + k0 + kc]) = lv;
}

// ---------------------------------------------------------------------------
// LayerNorm: one block per row; writes bf16 hi/lo pair planes.
// ---------------------------------------------------------------------------
__global__ __launch_bounds__(256) void ln_kernel(const float* __restrict__ in,
                                                 const float* __restrict__ g,
                                                 const float* __restrict__ b,
                                                 unsigned short* __restrict__ ohi,
                                                 unsigned short* __restrict__ olo) {
  const int row = blockIdx.x;
  const int t = threadIdx.x;
  float4 v = ld4(in + (size_t)row * D_ + t * 4);
  float s  = v.x + v.y + v.z + v.w;
  float ss = v.x * v.x + v.y * v.y + v.z * v.z + v.w * v.w;
  #pragma unroll
  for (int o = 32; o; o >>= 1) { s += __shfl_down(s, o); ss += __shfl_down(ss, o); }
  __shared__ float rs[4], rss[4];
  const int wid = t >> 6, lane = t & 63;
  if (lane == 0) { rs[wid] = s; rss[wid] = ss; }
  __syncthreads();
  s  = rs[0] + rs[1] + rs[2] + rs[3];
  ss = rss[0] + rss[1] + rss[2] + rss[3];
  const float mean = s * (1.f / D_);
  const float var  = ss * (1.f / D_) - mean * mean;
  const float rstd = rsqrtf(var + EPS_);
  float4 gv = ld4(g + t * 4);
  float4 bv = ld4(b + t * 4);
  float o0 = (v.x - mean) * rstd * gv.x + bv.x;
  float o1 = (v.y - mean) * rstd * gv.y + bv.y;
  float o2 = (v.z - mean) * rstd * gv.z + bv.z;
  float o3 = (v.w - mean) * rstd * gv.w + bv.w;
  ushort4 hv, lv;
  hv.x = bf16r(o0); lv.x = bf16r(o0 - bf2f(hv.x));
  hv.y = bf16r(o1); lv.y = bf16r(o1 - bf2f(hv.y));
  hv.z = bf16r(o2); lv.z = bf16r(o2 - bf2f(hv.z));
  hv.w = bf16r(o3); lv.w = bf16r(o3 - bf2f(hv.w));
  *reinterpret_cast<ushort4*>(&ohi[(size_t)row * D_ + t * 4]) = hv;
  *reinterpret_cast<ushort4*>(&olo[(size_t)row * D_ + t * 4]) = lv;
}

// ---------------------------------------------------------------------------
// Split-bf16 GEMM: C[M,N] = epi(A[M,K] @ W[K,N]), 3 MFMA products/step.
// A: hi/lo ushort [M][K]. B: transposed hi/lo ushort [N][K]. Tile 128x64,
// BK=32, 256 thr = 2x2 waves, wave-tile 64x32 (mf=4, nf=2), mfma 16x16x32.
// LDS rows padded to 40 ushorts (80 B stride -> ~2-way bank aliasing, free).
// ---------------------------------------------------------------------------
enum { GO_PAIR_BIAS = 0, GO_F32 = 1, GO_F32_BIAS_RESPAIR = 2,
       GO_F32_BIAS_RESF32 = 3, GO_F32_RES_NB = 4 };

template <int EPI>
__global__ __launch_bounds__(256) void gemm_sb(const unsigned short* __restrict__ Ah,
                                               const unsigned short* __restrict__ Al,
                                               const unsigned short* __restrict__ Bh,
                                               const unsigned short* __restrict__ Bl,
                                               const float* __restrict__ bias,
                                               const unsigned short* __restrict__ Rh,
                                               const unsigned short* __restrict__ Rl,
                                               const float* __restrict__ Rf,
                                               unsigned short* __restrict__ Ohi,
                                               unsigned short* __restrict__ Olo,
                                               float* __restrict__ Of,
                                               int M, int N, int K) {
  __shared__ unsigned short Ahs[128 * 40], Als[128 * 40];
  __shared__ unsigned short Bhs[64 * 40],  Bls[64 * 40];
  const int tid = threadIdx.x;
  const int m0 = blockIdx.y * 128, n0 = blockIdx.x * 64;
  const int lane = tid & 63, w = tid >> 6;
  const int wr = w >> 1, wc = w & 1;

  // staging geometry (ushort units; 16B chunks per thread)
  const int rA0 = tid >> 2, rA1 = 64 + (tid >> 2), chA = (tid & 3) * 8;
  const int rB = tid >> 2,  chB = (tid & 3) * 8;
  const size_t gA0 = (size_t)(m0 + rA0) * K + chA;
  const size_t gA1 = (size_t)(m0 + rA1) * K + chA;
  const size_t gB  = (size_t)(n0 + rB) * K + chB;
  const int lA0 = rA0 * 40 + chA, lA1 = rA1 * 40 + chA, lB = rB * 40 + chB;

  f32x4 acc[4][2];
  #pragma unroll
  for (int i = 0; i < 4; ++i)
    #pragma unroll
    for (int j = 0; j < 2; ++j) acc[i][j] = f32x4{0.f, 0.f, 0.f, 0.f};

  const int fr = lane & 15, fk = (lane >> 4) * 8;
  const int arow0 = (wr * 64 + fr) * 40 + fk;      // + mf*16*40
  const int brow0 = (wc * 32 + fr) * 40 + fk;      // + nf*16*40

  for (int k0 = 0; k0 < K; k0 += 32) {
    short8 a0h = *reinterpret_cast<const short8*>(&Ah[gA0 + k0]);
    short8 a1h = *reinterpret_cast<const short8*>(&Ah[gA1 + k0]);
    short8 a0l = *reinterpret_cast<const short8*>(&Al[gA0 + k0]);
    short8 a1l = *reinterpret_cast<const short8*>(&Al[gA1 + k0]);
    short8 bh  = *reinterpret_cast<const short8*>(&Bh[gB + k0]);
    short8 bl  = *reinterpret_cast<const short8*>(&Bl[gB + k0]);
    __syncthreads();                               // prev tile consumed
    *reinterpret_cast<short8*>(&Ahs[lA0]) = a0h;
    *reinterpret_cast<short8*>(&Ahs[lA1]) = a1h;
    *reinterpret_cast<short8*>(&Als[lA0]) = a0l;
    *reinterpret_cast<short8*>(&Als[lA1]) = a1l;
    *reinterpret_cast<short8*>(&Bhs[lB])  = bh;
    *reinterpret_cast<short8*>(&Bls[lB])  = bl;
    __syncthreads();

    short8 amh[4], aml[4], bnh[2], bnl[2];
    #pragma unroll
    for (int mf = 0; mf < 4; ++mf) {
      amh[mf] = *reinterpret_cast<const short8*>(&Ahs[arow0 + mf * 16 * 40]);
      aml[mf] = *reinterpret_cast<const short8*>(&Als[arow0 + mf * 16 * 40]);
    }
    #pragma unroll
    for (int nf = 0; nf < 2; ++nf) {
      bnh[nf] = *reinterpret_cast<const short8*>(&Bhs[brow0 + nf * 16 * 40]);
      bnl[nf] = *reinterpret_cast<const short8*>(&Bls[brow0 + nf * 16 * 40]);
    }
    #pragma unroll
    for (int mf = 0; mf < 4; ++mf)
      #pragma unroll
      for (int nf = 0; nf < 2; ++nf) {
        acc[mf][nf] = __builtin_amdgcn_mfma_f32_16x16x32_bf16(amh[mf], bnh[nf], acc[mf][nf], 0, 0, 0);
        acc[mf][nf] = __builtin_amdgcn_mfma_f32_16x16x32_bf16(amh[mf], bnl[nf], acc[mf][nf], 0, 0, 0);
        acc[mf][nf] = __builtin_amdgcn_mfma_f32_16x16x32_bf16(aml[mf], bnh[nf], acc[mf][nf], 0, 0, 0);
      }
  }

  // epilogue: D frag: row = (lane>>4)*4 + j, col = lane&15  (m89-verified)
  const int er = (lane >> 4) * 4, ec = lane & 15;
  #pragma unroll
  for (int mf = 0; mf < 4; ++mf)
    #pragma unroll
    for (int nf = 0; nf < 2; ++nf)
      #pragma unroll
      for (int j = 0; j < 4; ++j) {
        const int m = m0 + wr * 64 + mf * 16 + er + j;
        const int n = n0 + wc * 32 + nf * 16 + ec;
        float v = acc[mf][nf][j];
        if constexpr (EPI == GO_PAIR_BIAS || EPI == GO_F32_BIAS_RESPAIR ||
                      EPI == GO_F32_BIAS_RESF32) v += bias[n];
        const size_t idx = (size_t)m * N + n;
        if constexpr (EPI == GO_PAIR_BIAS) {
          unsigned short h = bf16r(v);
          Ohi[idx] = h; Olo[idx] = bf16r(v - bf2f(h));
        } else if constexpr (EPI == GO_F32) {
          Of[idx] = v;
        } else if constexpr (EPI == GO_F32_BIAS_RESPAIR) {
          Of[idx] = v + bf2f(Rh[idx]) + bf2f(Rl[idx]);
        } else {  // GO_F32_BIAS_RESF32 / GO_F32_RES_NB (Rf may alias Of)
          Of[idx] = v + Rf[idx];
        }
      }
}

// ---------------------------------------------------------------------------
// Dual GEMM (gate & up share A): f1 = silu(A@Wg+bg) * (A@Wu+bu), pair out.
// Operates on an N-chunk (caller offsets Wg/Wu/biases). Same tiling as gemm_sb.
// ---------------------------------------------------------------------------
__global__ __launch_bounds__(256) void gemm_gateup(const unsigned short* __restrict__ Ah,
                                                   const unsigned short* __restrict__ Al,
                                                   const unsigned short* __restrict__ Gh,
                                                   const unsigned short* __restrict__ Gl,
                                                   const unsigned short* __restrict__ Uh,
                                                   const unsigned short* __restrict__ Ul,
                                                   const float* __restrict__ bg,
                                                   const float* __restrict__ bu,
                                                   unsigned short* __restrict__ Ohi,
                                                   unsigned short* __restrict__ Olo,
                                                   int M, int N, int K) {
  __shared__ unsigned short Ahs[128 * 40], Als[128 * 40];
  __shared__ unsigned short Ghs[64 * 40], Gls[64 * 40], Uhs[64 * 40], Uls[64 * 40];
  const int tid = threadIdx.x;
  const int m0 = blockIdx.y * 128, n0 = blockIdx.x * 64;
  const int lane = tid & 63, w = tid >> 6;
  const int wr = w >> 1, wc = w & 1;

  const int rA0 = tid >> 2, rA1 = 64 + (tid >> 2), chA = (tid & 3) * 8;
  const int rB = tid >> 2, chB = (tid & 3) * 8;
  const size_t gA0 = (size_t)(m0 + rA0) * K + chA;
  const size_t gA1 = (size_t)(m0 + rA1) * K + chA;
  const size_t gB  = (size_t)(n0 + rB) * K + chB;
  const int lA0 = rA0 * 40 + chA, lA1 = rA1 * 40 + chA, lB = rB * 40 + chB;

  f32x4 accg[4][2], accu[4][2];
  #pragma unroll
  for (int i = 0; i < 4; ++i)
    #pragma unroll
    for (int j = 0; j < 2; ++j) {
      accg[i][j] = f32x4{0.f, 0.f, 0.f, 0.f};
      accu[i][j] = f32x4{0.f, 0.f, 0.f, 0.f};
    }

  const int fr = lane & 15, fk = (lane >> 4) * 8;
  const int arow0 = (wr * 64 + fr) * 40 + fk;
  const int brow0 = (wc * 32 + fr) * 40 + fk;

  for (int k0 = 0; k0 < K; k0 += 32) {
    short8 a0h = *reinterpret_cast<const short8*>(&Ah[gA0 + k0]);
    short8 a1h = *reinterpret_cast<const short8*>(&Ah[gA1 + k0]);
    short8 a0l = *reinterpret_cast<const short8*>(&Al[gA0 + k0]);
    short8 a1l = *reinterpret_cast<const short8*>(&Al[gA1 + k0]);
    short8 gh = *reinterpret_cast<const short8*>(&Gh[gB + k0]);
    short8 gl = *reinterpret_cast<const short8*>(&Gl[gB + k0]);
    short8 uh = *reinterpret_cast<const short8*>(&Uh[gB + k0]);
    short8 ul = *reinterpret_cast<const short8*>(&Ul[gB + k0]);
    __syncthreads();
    *reinterpret_cast<short8*>(&Ahs[lA0]) = a0h;
    *reinterpret_cast<short8*>(&Ahs[lA1]) = a1h;
    *reinterpret_cast<short8*>(&Als[lA0]) = a0l;
    *reinterpret_cast<short8*>(&Als[lA1]) = a1l;
    *reinterpret_cast<short8*>(&Ghs[lB]) = gh;
    *reinterpret_cast<short8*>(&Gls[lB]) = gl;
    *reinterpret_cast<short8*>(&Uhs[lB]) = uh;
    *reinterpret_cast<short8*>(&Uls[lB]) = ul;
    __syncthreads();

    short8 amh[4], aml[4];
    #pragma unroll
    for (int mf = 0; mf < 4; ++mf) {
      amh[mf] = *reinterpret_cast<const short8*>(&Ahs[arow0 + mf * 16 * 40]);
      aml[mf] = *reinterpret_cast<const short8*>(&Als[arow0 + mf * 16 * 40]);
    }
    #pragma unroll
    for (int nf = 0; nf < 2; ++nf) {
      short8 gnh = *reinterpret_cast<const short8*>(&Ghs[brow0 + nf * 16 * 40]);
      short8 gnl = *reinterpret_cast<const short8*>(&Gls[brow0 + nf * 16 * 40]);
      short8 unh = *reinterpret_cast<const short8*>(&Uhs[brow0 + nf * 16 * 40]);
      short8 unl = *reinterpret_cast<const short8*>(&Uls[brow0 + nf * 16 * 40]);
      #pragma unroll
      for (int mf = 0; mf < 4; ++mf) {
        accg[mf][nf] = __builtin_amdgcn_mfma_f32_16x16x32_bf16(amh[mf], gnh, accg[mf][nf], 0, 0, 0);
        accg[mf][nf] = __builtin_amdgcn_mfma_f32_16x16x32_bf16(amh[mf], gnl, accg[mf][nf], 0, 0, 0);
        accg[mf][nf] = __builtin_amdgcn_mfma_f32_16x16x32_bf16(aml[mf], gnh, accg[mf][nf], 0, 0, 0);
        accu[mf][nf] = __builtin_amdgcn_mfma_f32_16x16x32_bf16(amh[mf], unh, accu[mf][nf], 0, 0, 0);
        accu[mf][nf] = __builtin_amdgcn_mfma_f32_16x16x32_bf16(amh[mf], unl, accu[mf][nf], 0, 0, 0);
        accu[mf][nf] = __builtin_amdgcn_mfma_f32_16x16x32_bf16(aml[mf], unh, accu[mf][nf], 0, 0, 0);
      }
    }
  }

  const int er = (lane >> 4) * 4, ec = lane & 15;
  #pragma unroll
  for (int mf = 0; mf < 4; ++mf)
    #pragma unroll
    for (int nf = 0; nf < 2; ++nf)
      #pragma unroll
      for (int j = 0; j < 4; ++j) {
        const int m = m0 + wr * 64 + mf * 16 + er + j;
        const int n = n0 + wc * 32 + nf * 16 + ec;
        float g = accg[mf][nf][j] + bg[n];
        float u = accu[mf][nf][j] + bu[n];
        float f = (g / (1.f + expf(-g))) * u;
        const size_t idx = (size_t)m * N + n;
        unsigned short h = bf16r(f);
        Ohi[idx] = h; Olo[idx] = bf16r(f - bf2f(h));
      }
}

// ---------------------------------------------------------------------------
// Sparse attention (R2 structure; output bf16 pair)
// ---------------------------------------------------------------------------
__global__ __launch_bounds__(256) void attn_kernel(const float* __restrict__ qm,
                                                   const float* __restrict__ km,
                                                   const float* __restrict__ vm,
                                                   unsigned short* __restrict__ aoh,
                                                   unsigned short* __restrict__ aol,
                                                   const int* __restrict__ topk_p) {
  constexpr int QT = 4, CT = 128, NCH = N_ / CT;
  constexpr int NJ = 2 * NCH;
  __shared__ float Kc[CT][HD_];
  __shared__ float Pt[4][QT][CT];
  int*   selIdx = (int*)&Pt[0][0][0];
  float* selW   = (float*)&Pt[2][0][0];

  const int tid = threadIdx.x;
  const int bid = ((blockIdx.x & 7) << 11) | (blockIdx.x >> 3);
  const int qt = bid & (N_ / QT - 1);
  const int hh = (bid >> 9) & (H_ - 1);
  const int bb = bid >> 13;
  const int q0 = qt * QT;
  const size_t baseKV = (size_t)bb * N_ * D_ + (size_t)hh * HD_;
  const int lane = tid & 63;
  const int w = tid >> 6;
  const float scale = 0.125f;

  float4 qr[QT][4];
  #pragma unroll
  for (int r = 0; r < QT; ++r)
    #pragma unroll
    for (int dq = 0; dq < 4; ++dq) {
      float4 t = ld4(qm + baseKV + (size_t)(q0 + r) * D_ + w * 16 + dq * 4);
      t.x *= scale; t.y *= scale; t.z *= scale; t.w *= scale;
      qr[r][dq] = t;
    }

  unsigned key[NJ];
  for (int cb = 0; cb < NCH; ++cb) {
    float4 kst[8];
    #pragma unroll
    for (int it = 0; it < 8; ++it) {
      const int c = it * 16 + (tid >> 4);
      kst[it] = ld4(km + baseKV + (size_t)(cb * CT + c) * D_ + (tid & 15) * 4);
    }
    __syncthreads();
    #pragma unroll
    for (int it = 0; it < 8; ++it) {
      const int c = it * 16 + (tid >> 4);
      const int chk = (tid & 15) ^ (c & 15);
      st4(&Kc[c][chk * 4], kst[it]);
    }
    __syncthreads();

    float pa[QT][2];
    #pragma unroll
    for (int r = 0; r < QT; ++r) { pa[r][0] = 0.f; pa[r][1] = 0.f; }
    #pragma unroll
    for (int dq = 0; dq < 4; ++dq) {
      const int ch = w * 4 + dq;
      float4 k0 = ld4(&Kc[lane][(ch ^ (lane & 15)) * 4]);
      float4 k1 = ld4(&Kc[lane + 64][(ch ^ (lane & 15)) * 4]);
      #pragma unroll
      for (int r = 0; r < QT; ++r) {
        float4 qv = qr[r][dq];
        pa[r][0] += qv.x * k0.x + qv.y * k0.y + qv.z * k0.z + qv.w * k0.w;
        pa[r][1] += qv.x * k1.x + qv.y * k1.y + qv.z * k1.z + qv.w * k1.w;
      }
    }
    #pragma unroll
    for (int r = 0; r < QT; ++r) {
      Pt[w][r][lane]      = pa[r][0];
      Pt[w][r][lane + 64] = pa[r][1];
    }
    __syncthreads();
    {
      float s0 = Pt[0][w][lane] + Pt[1][w][lane] + Pt[2][w][lane] + Pt[3][w][lane];
      float s1 = Pt[0][w][lane + 64] + Pt[1][w][lane + 64] +
                 Pt[2][w][lane + 64] + Pt[3][w][lane + 64];
      key[2 * cb]     = fkey(s0);
      key[2 * cb + 1] = fkey(s1);
    }
  }

  int topk = *topk_p;
  if (topk > N_) topk = N_;

  unsigned kmax = 0;
  #pragma unroll
  for (int j = 0; j < NJ; ++j) kmax = (key[j] > kmax) ? key[j] : kmax;
  #pragma unroll
  for (int o = 32; o; o >>= 1) {
    unsigned t = __shfl_xor(kmax, o);
    kmax = (t > kmax) ? t : kmax;
  }
  const float smax = fval(kmax);

  unsigned thr = 0u;
  if (topk < N_) {
    for (int bit = 31; bit >= 0; --bit) {
      const unsigned cand = thr | (1u << bit);
      int c = 0;
      #pragma unroll
      for (int j = 0; j < NJ; ++j)
        c += __popcll(__ballot(key[j] >= cand));
      if (c >= topk) thr = cand;
    }
  }

  __syncthreads();
  int base = 0;
  float wpart = 0.f;
  #pragma unroll
  for (int j = 0; j < NJ; ++j) {
    const bool sel = key[j] >= thr;
    const unsigned long long m = __ballot(sel);
    if (sel) {
      const int pos = base + (int)__popcll(m & ((1ull << lane) - 1ull));
      if (pos < 128) {
        const float wgt = expf(fval(key[j]) - smax);
        selIdx[w * 128 + pos] = j * 64 + lane;
        selW[w * 128 + pos] = wgt;
        wpart += wgt;
      }
    }
    base += (int)__popcll(m);
  }
  int cnt = (base > 128) ? 128 : base;
  float wsum = wpart;
  #pragma unroll
  for (int o = 32; o; o >>= 1) wsum += __shfl_xor(wsum, o);

  const float* Vb = vm + baseKV;
  float outv = 0.f;
  int i = 0;
  for (; i + 16 <= cnt; i += 16) {
    int ix[16]; float wv[16], vv[16];
    #pragma unroll
    for (int t = 0; t < 16; ++t) {
      ix[t] = selIdx[w * 128 + i + t];
      wv[t] = selW[w * 128 + i + t];
    }
    #pragma unroll
    for (int t = 0; t < 16; ++t) vv[t] = Vb[(size_t)ix[t] * D_ + lane];
    #pragma unroll
    for (int t = 0; t < 16; ++t) outv += wv[t] * vv[t];
  }
  for (; i < cnt; ++i)
    outv += selW[w * 128 + i] * Vb[(size_t)selIdx[w * 128 + i] * D_ + lane];

  const float o = outv / wsum;
  const size_t oidx = ((size_t)bb * N_ + q0 + w) * D_ + hh * HD_ + lane;
  unsigned short h = bf16r(o);
  aoh[oidx] = h; aol[oidx] = bf16r(o - bf2f(h));
}

// ---------------------------------------------------------------------------
// Orchestration. ws extent = 100 MB (< 112 MB proven-safe). Aliasing by
// lifetime (all launches stream-ordered):
//   [0,16)   Wi/Wq/Wk/Wv pairs -> ao pair (post-QKV) -> f1_lo chunk (post-wo)
//   [16,20)  Wo pair
//   [20,36)  Wd chunk pairs (c0_h,c0_l,c1_h,c1_l; 4 MB each)
//   [36,52)  hp pair -> ff pair (post-wo)
//   [52,100) xn pair | qb,kb,vb f32 | Wg+Wu pairs (post-attn) + f1_hi chunk
//   h2 lives in d_out (wo-gemm writes it; LN2 reads; down-proj in-place).
// ---------------------------------------------------------------------------
extern "C" void kernel_launch(void* const* d_in, const int* in_sizes, int n_in,
                              void* d_out, int out_size, void* d_ws, size_t ws_size,
                              hipStream_t stream) {
  const float* x      = (const float*)d_in[0];
  const float* ln1_g  = (const float*)d_in[1];
  const float* ln1_b  = (const float*)d_in[2];
  const float* w_in   = (const float*)d_in[3];
  const float* b_in   = (const float*)d_in[4];
  const float* wq     = (const float*)d_in[5];
  const float* wk     = (const float*)d_in[6];
  const float* wv     = (const float*)d_in[7];
  const float* wo     = (const float*)d_in[8];
  const float* bo     = (const float*)d_in[9];
  const float* ln2_g  = (const float*)d_in[10];
  const float* ln2_b  = (const float*)d_in[11];
  const float* w_up   = (const float*)d_in[12];
  const float* b_up   = (const float*)d_in[13];
  const float* w_gate = (const float*)d_in[14];
  const float* b_gate = (const float*)d_in[15];
  const float* w_down = (const float*)d_in[16];
  const float* b_down = (const float*)d_in[17];
  const int*   topk   = (const int*)d_in[18];
  float* out = (float*)d_out;

  char* p = (char*)d_ws;
  const size_t MB = 1024 * 1024;
  // small weight pairs [0,20)
  unsigned short* Wi_h = (unsigned short*)(p + 0 * MB);
  unsigned short* Wi_l = (unsigned short*)(p + 2 * MB);
  unsigned short* Wq_h = (unsigned short*)(p + 4 * MB);
  unsigned short* Wq_l = (unsigned short*)(p + 6 * MB);
  unsigned short* Wk_h = (unsigned short*)(p + 8 * MB);
  unsigned short* Wk_l = (unsigned short*)(p + 10 * MB);
  unsigned short* Wv_h = (unsigned short*)(p + 12 * MB);
  unsigned short* Wv_l = (unsigned short*)(p + 14 * MB);
  unsigned short* Wo_h = (unsigned short*)(p + 16 * MB);
  unsigned short* Wo_l = (unsigned short*)(p + 18 * MB);
  // w_down chunk pairs [20,36): [1024][2048] each plane (4 MB)
  unsigned short* Wd0_h = (unsigned short*)(p + 20 * MB);
  unsigned short* Wd0_l = (unsigned short*)(p + 24 * MB);
  unsigned short* Wd1_h = (unsigned short*)(p + 28 * MB);
  unsigned short* Wd1_l = (unsigned short*)(p + 32 * MB);
  // [36,52): hp pair, later ff pair
  unsigned short* hp_h = (unsigned short*)(p + 36 * MB);
  unsigned short* hp_l = (unsigned short*)(p + 44 * MB);
  unsigned short* ff_h = (unsigned short*)(p + 36 * MB);
  unsigned short* ff_l = (unsigned short*)(p + 44 * MB);
  // [52,100): xn pair | qb,kb,vb | Wg/Wu pairs + f1_hi
  unsigned short* xn_h = (unsigned short*)(p + 52 * MB);
  unsigned short* xn_l = (unsigned short*)(p + 60 * MB);
  float*          qb   = (float*)(p + 52 * MB);
  float*          kb   = (float*)(p + 68 * MB);
  float*          vb   = (float*)(p + 84 * MB);
  unsigned short* Wg_h = (unsigned short*)(p + 52 * MB);
  unsigned short* Wg_l = (unsigned short*)(p + 60 * MB);
  unsigned short* Wu_h = (unsigned short*)(p + 68 * MB);
  unsigned short* Wu_l = (unsigned short*)(p + 76 * MB);
  unsigned short* f1_h = (unsigned short*)(p + 84 * MB);   // [4096][2048] chunk
  // ao pair + f1_lo alias the dead small-weight region [0,16)
  unsigned short* ao_h = (unsigned short*)(p + 0 * MB);
  unsigned short* ao_l = (unsigned short*)(p + 8 * MB);
  unsigned short* f1_l = (unsigned short*)(p + 0 * MB);    // [4096][2048] chunk

  const dim3 blk(256);
  const dim3 gW1k(32, 32);     // 1024x1024 wconv
  const dim3 gWgu(128, 32);    // K=1024, N=4096 wconv
  const dim3 gWd(32, 64);      // K=2048, N=1024 wconv (per chunk)
  const dim3 g1024(16, 32);    // N=1024 GEMM
  const dim3 g2048(32, 32);    // N=2048 chunked gateup

  // --- weight conversions (small + down chunks) ---
  wconv_kernel<<<gW1k, blk, 0, stream>>>(w_in, Wi_h, Wi_l, 1024, 1024);
  wconv_kernel<<<gW1k, blk, 0, stream>>>(wq, Wq_h, Wq_l, 1024, 1024);
  wconv_kernel<<<gW1k, blk, 0, stream>>>(wk, Wk_h, Wk_l, 1024, 1024);
  wconv_kernel<<<gW1k, blk, 0, stream>>>(wv, Wv_h, Wv_l, 1024, 1024);
  wconv_kernel<<<gW1k, blk, 0, stream>>>(wo, Wo_h, Wo_l, 1024, 1024);
  wconv_kernel<<<gWd, blk, 0, stream>>>(w_down,               Wd0_h, Wd0_l, 2048, 1024);
  wconv_kernel<<<gWd, blk, 0, stream>>>(w_down + 2048 * 1024, Wd1_h, Wd1_l, 2048, 1024);

  // --- LN1 -> gemm chain ---
  ln_kernel<<<M_, blk, 0, stream>>>(x, ln1_g, ln1_b, xn_h, xn_l);
  gemm_sb<GO_PAIR_BIAS><<<g1024, blk, 0, stream>>>(xn_h, xn_l, Wi_h, Wi_l, b_in,
      nullptr, nullptr, nullptr, hp_h, hp_l, nullptr, M_, 1024, 1024);
  gemm_sb<GO_F32><<<g1024, blk, 0, stream>>>(hp_h, hp_l, Wq_h, Wq_l, nullptr,
      nullptr, nullptr, nullptr, nullptr, nullptr, qb, M_, 1024, 1024);
  gemm_sb<GO_F32><<<g1024, blk, 0, stream>>>(hp_h, hp_l, Wk_h, Wk_l, nullptr,
      nullptr, nullptr, nullptr, nullptr, nullptr, kb, M_, 1024, 1024);
  gemm_sb<GO_F32><<<g1024, blk, 0, stream>>>(hp_h, hp_l, Wv_h, Wv_l, nullptr,
      nullptr, nullptr, nullptr, nullptr, nullptr, vb, M_, 1024, 1024);

  // --- attention (writes ao into dead Wi..Wv region) ---
  attn_kernel<<<B_ * H_ * (N_ / 4), blk, 0, stream>>>(qb, kb, vb, ao_h, ao_l, topk);

  // --- convert Wg/Wu into dead q/k slots ---
  wconv_kernel<<<gWgu, blk, 0, stream>>>(w_gate, Wg_h, Wg_l, 1024, 4096);
  wconv_kernel<<<gWgu, blk, 0, stream>>>(w_up,   Wu_h, Wu_l, 1024, 4096);

  // --- wo-gemm: h2 = ao@Wo + bo + hp  -> d_out ---
  gemm_sb<GO_F32_BIAS_RESPAIR><<<g1024, blk, 0, stream>>>(ao_h, ao_l, Wo_h, Wo_l, bo,
      hp_h, hp_l, nullptr, nullptr, nullptr, out, M_, 1024, 1024);

  // --- LN2 (reads d_out) -> ff pair (hp slot, dead) ---
  ln_kernel<<<M_, blk, 0, stream>>>(out, ln2_g, ln2_b, ff_h, ff_l);

  // --- FFN in two N-chunks of 2048; down-proj accumulates in-place in d_out ---
  // chunk 0
  gemm_gateup<<<g2048, blk, 0, stream>>>(ff_h, ff_l,
      Wg_h, Wg_l, Wu_h, Wu_l, b_gate, b_up, f1_h, f1_l, M_, 2048, 1024);
  gemm_sb<GO_F32_BIAS_RESF32><<<g1024, blk, 0, stream>>>(f1_h, f1_l, Wd0_h, Wd0_l,
      b_down, nullptr, nullptr, out, nullptr, nullptr, out, M_, 1024, 2048);
  // chunk 1
  gemm_gateup<<<g2048, blk, 0, stream>>>(ff_h, ff_l,
      Wg_h + (size_t)2048 * 1024, Wg_l + (size_t)2048 * 1024,
      Wu_h + (size_t)2048 * 1024, Wu_l + (size_t)2048 * 1024,
      b_gate + 2048, b_up + 2048, f1_h, f1_l, M_, 2048, 1024);
  gemm_sb<GO_F32_RES_NB><<<g1024, blk, 0, stream>>>(f1_h, f1_l, Wd1_h, Wd1_l,
      nullptr, nullptr, nullptr, out, nullptr, nullptr, out, M_, 1024, 2048);
}

// Round 7
// 1333.325 us; speedup vs baseline: 2.6019x; 1.1372x over previous
//
#include <hip/hip_runtime.h>
#include <cstdint>

// ============================================================================
// ScaledCorticalColumn — R7 (= R5/R6 resubmit; never ran due to infra):
// attention QK^T moved to split-bf16 MFMA.
//   - q/k produced as bf16 hi/lo pairs by their GEMM epilogues (GO_PAIR_NB)
//   - attn: QBLK=16/block; per-wave 16x512 score quadrant via 192 MFMA;
//     B-frags direct from L2 (XCD-local K); LDS redistribution to the
//     verified radix-select layout; early-exit radix; deferred expf;
//     compacted parallel V-gather (R2-proven).
// GEMM/LN/wconv stack unchanged from R4 (clean A/B on attention).
// ============================================================================

#define DEV __device__ __forceinline__

constexpr int B_  = 2;
constexpr int N_  = 2048;
constexpr int D_  = 1024;
constexpr int H_  = 16;
constexpr int HD_ = 64;
constexpr int M_  = B_ * N_;          // 4096 rows
constexpr float EPS_ = 1e-5f;

using short8 = __attribute__((ext_vector_type(8))) short;
using f32x4  = __attribute__((ext_vector_type(4))) float;

DEV float4 ld4(const float* p) { return *reinterpret_cast<const float4*>(p); }
DEV void   st4(float* p, float4 v) { *reinterpret_cast<float4*>(p) = v; }

// bf16 round-to-nearest-even split helpers
DEV unsigned short bf16r(float x) {
  unsigned u = __float_as_uint(x);
  u += 0x7fffu + ((u >> 16) & 1u);
  return (unsigned short)(u >> 16);
}
DEV float bf2f(unsigned short h) { return __uint_as_float(((unsigned)h) << 16); }

// order-preserving float<->uint key map (monotone bijection, tie-exact)
DEV unsigned fkey(float f) {
  unsigned u = __float_as_uint(f);
  return u ^ ((unsigned)((int)u >> 31) | 0x80000000u);
}
DEV float fval(unsigned k) {
  unsigned u = (k & 0x80000000u) ? (k ^ 0x80000000u) : ~k;
  return __uint_as_float(u);
}

// ---------------------------------------------------------------------------
// Weight transpose-convert: W f32 [K][N] -> Thi/Tlo bf16 [N][K]. 32x32 tiles.
// ---------------------------------------------------------------------------
__global__ __launch_bounds__(256) void wconv_kernel(const float* __restrict__ W,
                                                    unsigned short* __restrict__ Thi,
                                                    unsigned short* __restrict__ Tlo,
                                                    int K, int N) {
  __shared__ float t[32][33];
  const int k0 = blockIdx.y * 32, n0 = blockIdx.x * 32;
  const int tid = threadIdx.x;
  const int r = tid >> 3, c4 = (tid & 7) * 4;
  float4 v = ld4(W + (size_t)(k0 + r) * N + n0 + c4);
  t[r][c4 + 0] = v.x; t[r][c4 + 1] = v.y; t[r][c4 + 2] = v.z; t[r][c4 + 3] = v.w;
  __syncthreads();
  const int n = tid >> 3, kc = (tid & 7) * 4;
  ushort4 hv, lv;
  {
    float x0 = t[kc + 0][n], x1 = t[kc + 1][n], x2 = t[kc + 2][n], x3 = t[kc + 3][n];
    hv.x = bf16r(x0); lv.x = bf16r(x0 - bf2f(hv.x));
    hv.y = bf16r(x1); lv.y = bf16r(x1 - bf2f(hv.y));
    hv.z = bf16r(x2); lv.z = bf16r(x2 - bf2f(hv.z));
    hv.w = bf16r(x3); lv.w = bf16r(x3 - bf2f(hv.w));
  }
  *reinterpret_cast<ushort4*>(&Thi[(size_t)(n0 + n) * K + k0 + kc]) = hv;
  *reinterpret_cast<ushort4*>(&Tlo[(size_t)(n0 + n) * K + k0 + kc]) = lv;
}

// ---------------------------------------------------------------------------
// LayerNorm: one block per row; writes bf16 hi/lo pair planes.
// ---------------------------------------------------------------------------
__global__ __launch_bounds__(256) void ln_kernel(const float* __restrict__ in,
                                                 const float* __restrict__ g,
                                                 const float* __restrict__ b,
                                                 unsigned short* __restrict__ ohi,
                                                 unsigned short* __restrict__ olo) {
  const int row = blockIdx.x;
  const int t = threadIdx.x;
  float4 v = ld4(in + (size_t)row * D_ + t * 4);
  float s  = v.x + v.y + v.z + v.w;
  float ss = v.x * v.x + v.y * v.y + v.z * v.z + v.w * v.w;
  #pragma unroll
  for (int o = 32; o; o >>= 1) { s += __shfl_down(s, o); ss += __shfl_down(ss, o); }
  __shared__ float rs[4], rss[4];
  const int wid = t >> 6, lane = t & 63;
  if (lane == 0) { rs[wid] = s; rss[wid] = ss; }
  __syncthreads();
  s  = rs[0] + rs[1] + rs[2] + rs[3];
  ss = rss[0] + rss[1] + rss[2] + rss[3];
  const float mean = s * (1.f / D_);
  const float var  = ss * (1.f / D_) - mean * mean;
  const float rstd = rsqrtf(var + EPS_);
  float4 gv = ld4(g + t * 4);
  float4 bv = ld4(b + t * 4);
  float o0 = (v.x - mean) * rstd * gv.x + bv.x;
  float o1 = (v.y - mean) * rstd * gv.y + bv.y;
  float o2 = (v.z - mean) * rstd * gv.z + bv.z;
  float o3 = (v.w - mean) * rstd * gv.w + bv.w;
  ushort4 hv, lv;
  hv.x = bf16r(o0); lv.x = bf16r(o0 - bf2f(hv.x));
  hv.y = bf16r(o1); lv.y = bf16r(o1 - bf2f(hv.y));
  hv.z = bf16r(o2); lv.z = bf16r(o2 - bf2f(hv.z));
  hv.w = bf16r(o3); lv.w = bf16r(o3 - bf2f(hv.w));
  *reinterpret_cast<ushort4*>(&ohi[(size_t)row * D_ + t * 4]) = hv;
  *reinterpret_cast<ushort4*>(&olo[(size_t)row * D_ + t * 4]) = lv;
}

// ---------------------------------------------------------------------------
// Split-bf16 GEMM (tiling unchanged from R4; GO_PAIR_NB epilogue for q/k)
// ---------------------------------------------------------------------------
enum { GO_PAIR_BIAS = 0, GO_F32 = 1, GO_F32_BIAS_RESPAIR = 2,
       GO_F32_BIAS_RESF32 = 3, GO_F32_RES_NB = 4, GO_PAIR_NB = 5 };

template <int EPI>
__global__ __launch_bounds__(256) void gemm_sb(const unsigned short* __restrict__ Ah,
                                               const unsigned short* __restrict__ Al,
                                               const unsigned short* __restrict__ Bh,
                                               const unsigned short* __restrict__ Bl,
                                               const float* __restrict__ bias,
                                               const unsigned short* __restrict__ Rh,
                                               const unsigned short* __restrict__ Rl,
                                               const float* __restrict__ Rf,
                                               unsigned short* __restrict__ Ohi,
                                               unsigned short* __restrict__ Olo,
                                               float* __restrict__ Of,
                                               int M, int N, int K) {
  __shared__ unsigned short Ahs[128 * 40], Als[128 * 40];
  __shared__ unsigned short Bhs[64 * 40],  Bls[64 * 40];
  const int tid = threadIdx.x;
  const int m0 = blockIdx.y * 128, n0 = blockIdx.x * 64;
  const int lane = tid & 63, w = tid >> 6;
  const int wr = w >> 1, wc = w & 1;

  const int rA0 = tid >> 2, rA1 = 64 + (tid >> 2), chA = (tid & 3) * 8;
  const int rB = tid >> 2,  chB = (tid & 3) * 8;
  const size_t gA0 = (size_t)(m0 + rA0) * K + chA;
  const size_t gA1 = (size_t)(m0 + rA1) * K + chA;
  const size_t gB  = (size_t)(n0 + rB) * K + chB;
  const int lA0 = rA0 * 40 + chA, lA1 = rA1 * 40 + chA, lB = rB * 40 + chB;

  f32x4 acc[4][2];
  #pragma unroll
  for (int i = 0; i < 4; ++i)
    #pragma unroll
    for (int j = 0; j < 2; ++j) acc[i][j] = f32x4{0.f, 0.f, 0.f, 0.f};

  const int fr = lane & 15, fk = (lane >> 4) * 8;
  const int arow0 = (wr * 64 + fr) * 40 + fk;
  const int brow0 = (wc * 32 + fr) * 40 + fk;

  for (int k0 = 0; k0 < K; k0 += 32) {
    short8 a0h = *reinterpret_cast<const short8*>(&Ah[gA0 + k0]);
    short8 a1h = *reinterpret_cast<const short8*>(&Ah[gA1 + k0]);
    short8 a0l = *reinterpret_cast<const short8*>(&Al[gA0 + k0]);
    short8 a1l = *reinterpret_cast<const short8*>(&Al[gA1 + k0]);
    short8 bh  = *reinterpret_cast<const short8*>(&Bh[gB + k0]);
    short8 bl  = *reinterpret_cast<const short8*>(&Bl[gB + k0]);
    __syncthreads();
    *reinterpret_cast<short8*>(&Ahs[lA0]) = a0h;
    *reinterpret_cast<short8*>(&Ahs[lA1]) = a1h;
    *reinterpret_cast<short8*>(&Als[lA0]) = a0l;
    *reinterpret_cast<short8*>(&Als[lA1]) = a1l;
    *reinterpret_cast<short8*>(&Bhs[lB])  = bh;
    *reinterpret_cast<short8*>(&Bls[lB])  = bl;
    __syncthreads();

    short8 amh[4], aml[4], bnh[2], bnl[2];
    #pragma unroll
    for (int mf = 0; mf < 4; ++mf) {
      amh[mf] = *reinterpret_cast<const short8*>(&Ahs[arow0 + mf * 16 * 40]);
      aml[mf] = *reinterpret_cast<const short8*>(&Als[arow0 + mf * 16 * 40]);
    }
    #pragma unroll
    for (int nf = 0; nf < 2; ++nf) {
      bnh[nf] = *reinterpret_cast<const short8*>(&Bhs[brow0 + nf * 16 * 40]);
      bnl[nf] = *reinterpret_cast<const short8*>(&Bls[brow0 + nf * 16 * 40]);
    }
    #pragma unroll
    for (int mf = 0; mf < 4; ++mf)
      #pragma unroll
      for (int nf = 0; nf < 2; ++nf) {
        acc[mf][nf] = __builtin_amdgcn_mfma_f32_16x16x32_bf16(amh[mf], bnh[nf], acc[mf][nf], 0, 0, 0);
        acc[mf][nf] = __builtin_amdgcn_mfma_f32_16x16x32_bf16(amh[mf], bnl[nf], acc[mf][nf], 0, 0, 0);
        acc[mf][nf] = __builtin_amdgcn_mfma_f32_16x16x32_bf16(aml[mf], bnh[nf], acc[mf][nf], 0, 0, 0);
      }
  }

  const int er = (lane >> 4) * 4, ec = lane & 15;
  #pragma unroll
  for (int mf = 0; mf < 4; ++mf)
    #pragma unroll
    for (int nf = 0; nf < 2; ++nf)
      #pragma unroll
      for (int j = 0; j < 4; ++j) {
        const int m = m0 + wr * 64 + mf * 16 + er + j;
        const int n = n0 + wc * 32 + nf * 16 + ec;
        float v = acc[mf][nf][j];
        if constexpr (EPI == GO_PAIR_BIAS || EPI == GO_F32_BIAS_RESPAIR ||
                      EPI == GO_F32_BIAS_RESF32) v += bias[n];
        const size_t idx = (size_t)m * N + n;
        if constexpr (EPI == GO_PAIR_BIAS || EPI == GO_PAIR_NB) {
          unsigned short h = bf16r(v);
          Ohi[idx] = h; Olo[idx] = bf16r(v - bf2f(h));
        } else if constexpr (EPI == GO_F32) {
          Of[idx] = v;
        } else if constexpr (EPI == GO_F32_BIAS_RESPAIR) {
          Of[idx] = v + bf2f(Rh[idx]) + bf2f(Rl[idx]);
        } else {  // GO_F32_BIAS_RESF32 / GO_F32_RES_NB (Rf may alias Of)
          Of[idx] = v + Rf[idx];
        }
      }
}

// ---------------------------------------------------------------------------
// Dual GEMM (gate & up share A) — unchanged from R4
// ---------------------------------------------------------------------------
__global__ __launch_bounds__(256) void gemm_gateup(const unsigned short* __restrict__ Ah,
                                                   const unsigned short* __restrict__ Al,
                                                   const unsigned short* __restrict__ Gh,
                                                   const unsigned short* __restrict__ Gl,
                                                   const unsigned short* __restrict__ Uh,
                                                   const unsigned short* __restrict__ Ul,
                                                   const float* __restrict__ bg,
                                                   const float* __restrict__ bu,
                                                   unsigned short* __restrict__ Ohi,
                                                   unsigned short* __restrict__ Olo,
                                                   int M, int N, int K) {
  __shared__ unsigned short Ahs[128 * 40], Als[128 * 40];
  __shared__ unsigned short Ghs[64 * 40], Gls[64 * 40], Uhs[64 * 40], Uls[64 * 40];
  const int tid = threadIdx.x;
  const int m0 = blockIdx.y * 128, n0 = blockIdx.x * 64;
  const int lane = tid & 63, w = tid >> 6;
  const int wr = w >> 1, wc = w & 1;

  const int rA0 = tid >> 2, rA1 = 64 + (tid >> 2), chA = (tid & 3) * 8;
  const int rB = tid >> 2, chB = (tid & 3) * 8;
  const size_t gA0 = (size_t)(m0 + rA0) * K + chA;
  const size_t gA1 = (size_t)(m0 + rA1) * K + chA;
  const size_t gB  = (size_t)(n0 + rB) * K + chB;
  const int lA0 = rA0 * 40 + chA, lA1 = rA1 * 40 + chA, lB = rB * 40 + chB;

  f32x4 accg[4][2], accu[4][2];
  #pragma unroll
  for (int i = 0; i < 4; ++i)
    #pragma unroll
    for (int j = 0; j < 2; ++j) {
      accg[i][j] = f32x4{0.f, 0.f, 0.f, 0.f};
      accu[i][j] = f32x4{0.f, 0.f, 0.f, 0.f};
    }

  const int fr = lane & 15, fk = (lane >> 4) * 8;
  const int arow0 = (wr * 64 + fr) * 40 + fk;
  const int brow0 = (wc * 32 + fr) * 40 + fk;

  for (int k0 = 0; k0 < K; k0 += 32) {
    short8 a0h = *reinterpret_cast<const short8*>(&Ah[gA0 + k0]);
    short8 a1h = *reinterpret_cast<const short8*>(&Ah[gA1 + k0]);
    short8 a0l = *reinterpret_cast<const short8*>(&Al[gA0 + k0]);
    short8 a1l = *reinterpret_cast<const short8*>(&Al[gA1 + k0]);
    short8 gh = *reinterpret_cast<const short8*>(&Gh[gB + k0]);
    short8 gl = *reinterpret_cast<const short8*>(&Gl[gB + k0]);
    short8 uh = *reinterpret_cast<const short8*>(&Uh[gB + k0]);
    short8 ul = *reinterpret_cast<const short8*>(&Ul[gB + k0]);
    __syncthreads();
    *reinterpret_cast<short8*>(&Ahs[lA0]) = a0h;
    *reinterpret_cast<short8*>(&Ahs[lA1]) = a1h;
    *reinterpret_cast<short8*>(&Als[lA0]) = a0l;
    *reinterpret_cast<short8*>(&Als[lA1]) = a1l;
    *reinterpret_cast<short8*>(&Ghs[lB]) = gh;
    *reinterpret_cast<short8*>(&Gls[lB]) = gl;
    *reinterpret_cast<short8*>(&Uhs[lB]) = uh;
    *reinterpret_cast<short8*>(&Uls[lB]) = ul;
    __syncthreads();

    short8 amh[4], aml[4];
    #pragma unroll
    for (int mf = 0; mf < 4; ++mf) {
      amh[mf] = *reinterpret_cast<const short8*>(&Ahs[arow0 + mf * 16 * 40]);
      aml[mf] = *reinterpret_cast<const short8*>(&Als[arow0 + mf * 16 * 40]);
    }
    #pragma unroll
    for (int nf = 0; nf < 2; ++nf) {
      short8 gnh = *reinterpret_cast<const short8*>(&Ghs[brow0 + nf * 16 * 40]);
      short8 gnl = *reinterpret_cast<const short8*>(&Gls[brow0 + nf * 16 * 40]);
      short8 unh = *reinterpret_cast<const short8*>(&Uhs[brow0 + nf * 16 * 40]);
      short8 unl = *reinterpret_cast<const short8*>(&Uls[brow0 + nf * 16 * 40]);
      #pragma unroll
      for (int mf = 0; mf < 4; ++mf) {
        accg[mf][nf] = __builtin_amdgcn_mfma_f32_16x16x32_bf16(amh[mf], gnh, accg[mf][nf], 0, 0, 0);
        accg[mf][nf] = __builtin_amdgcn_mfma_f32_16x16x32_bf16(amh[mf], gnl, accg[mf][nf], 0, 0, 0);
        accg[mf][nf] = __builtin_amdgcn_mfma_f32_16x16x32_bf16(aml[mf], gnh, accg[mf][nf], 0, 0, 0);
        accu[mf][nf] = __builtin_amdgcn_mfma_f32_16x16x32_bf16(amh[mf], unh, accu[mf][nf], 0, 0, 0);
        accu[mf][nf] = __builtin_amdgcn_mfma_f32_16x16x32_bf16(amh[mf], unl, accu[mf][nf], 0, 0, 0);
        accu[mf][nf] = __builtin_amdgcn_mfma_f32_16x16x32_bf16(aml[mf], unh, accu[mf][nf], 0, 0, 0);
      }
    }
  }

  const int er = (lane >> 4) * 4, ec = lane & 15;
  #pragma unroll
  for (int mf = 0; mf < 4; ++mf)
    #pragma unroll
    for (int nf = 0; nf < 2; ++nf)
      #pragma unroll
      for (int j = 0; j < 4; ++j) {
        const int m = m0 + wr * 64 + mf * 16 + er + j;
        const int n = n0 + wc * 32 + nf * 16 + ec;
        float g = accg[mf][nf][j] + bg[n];
        float u = accu[mf][nf][j] + bu[n];
        float f = (g / (1.f + expf(-g))) * u;
        const size_t idx = (size_t)m * N + n;
        unsigned short h = bf16r(f);
        Ohi[idx] = h; Olo[idx] = bf16r(f - bf2f(h));
      }
}

// ---------------------------------------------------------------------------
// Sparse attention v3: QBLK=16 rows/block, 4 waves.
//  phase 1: wave w computes 16x512 score quadrant (cols [512w,512w+512)) via
//           split-bf16 MFMA 16x16x32; A-frags from q pair, B-frags direct
//           from k pair in global (L2-resident via XCD swizzle).
//  phase 1.5: 4-round LDS redistribution (Sb[16][513]) -> key[4][32] regs,
//           wave w owns rows {w, w+4, w+8, w+12}; scale *0.125 applied (exact).
//  phase 2: per row: exact kth-largest radix-select (early exit at c==topk,
//           set-exact: {key>=thr} with count==topk IS the top-k set).
//  phase 3: compaction (raw scores), deferred expf (2/lane), batched V gather.
// LDS: 32.8 KB Sb + 4 KB sel = 37 KB.
// ---------------------------------------------------------------------------
__global__ __launch_bounds__(256) void attn_kernel(
    const unsigned short* __restrict__ qh, const unsigned short* __restrict__ ql,
    const unsigned short* __restrict__ kh, const unsigned short* __restrict__ kl,
    const float* __restrict__ vm,
    unsigned short* __restrict__ aoh, unsigned short* __restrict__ aol,
    const int* __restrict__ topk_p) {
  constexpr int QB = 16;
  constexpr int NJ = N_ / 64;               // 32 keys/lane/row
  __shared__ float Sb[QB][513];             // 32.8 KB redistribution chunk
  __shared__ int   selIdx[4][128];
  __shared__ float selS[4][128];

  const int tid = threadIdx.x;
  const int lane = tid & 63, w = tid >> 6;
  // XCD-chunked bijective swizzle: 4096 = 8 XCDs x 512
  const int bid = ((blockIdx.x & 7) << 9) | (blockIdx.x >> 3);
  const int qt = bid & 127;
  const int hh = (bid >> 7) & (H_ - 1);
  const int bb = bid >> 11;
  const int q0 = qt * QB;

  const int fr = lane & 15;                 // frag row (A) / col (B)
  const int fk = (lane >> 4) * 8;           // frag k-offset (bf16 units)

  // ---- phase 1: MFMA QK^T, wave-quadrant cols [512w, 512w+512) ----
  const size_t qbase = ((size_t)(bb * N_ + q0 + fr)) * D_ + hh * HD_ + fk;
  short8 ah0 = *reinterpret_cast<const short8*>(qh + qbase);
  short8 ah1 = *reinterpret_cast<const short8*>(qh + qbase + 32);
  short8 al0 = *reinterpret_cast<const short8*>(ql + qbase);
  short8 al1 = *reinterpret_cast<const short8*>(ql + qbase + 32);

  const int c0 = w * 512;
  const size_t kwb = ((size_t)(bb * N_ + c0 + fr)) * D_ + hh * HD_ + fk;

  f32x4 acc[32];
  #pragma unroll
  for (int ct = 0; ct < 32; ++ct) acc[ct] = f32x4{0.f, 0.f, 0.f, 0.f};

  #pragma unroll
  for (int ct = 0; ct < 32; ++ct) {
    const size_t kb0 = kwb + (size_t)ct * 16 * D_;
    short8 bh0 = *reinterpret_cast<const short8*>(kh + kb0);
    short8 bh1 = *reinterpret_cast<const short8*>(kh + kb0 + 32);
    short8 bl0 = *reinterpret_cast<const short8*>(kl + kb0);
    short8 bl1 = *reinterpret_cast<const short8*>(kl + kb0 + 32);
    acc[ct] = __builtin_amdgcn_mfma_f32_16x16x32_bf16(ah0, bh0, acc[ct], 0, 0, 0);
    acc[ct] = __builtin_amdgcn_mfma_f32_16x16x32_bf16(ah0, bl0, acc[ct], 0, 0, 0);
    acc[ct] = __builtin_amdgcn_mfma_f32_16x16x32_bf16(al0, bh0, acc[ct], 0, 0, 0);
    acc[ct] = __builtin_amdgcn_mfma_f32_16x16x32_bf16(ah1, bh1, acc[ct], 0, 0, 0);
    acc[ct] = __builtin_amdgcn_mfma_f32_16x16x32_bf16(ah1, bl1, acc[ct], 0, 0, 0);
    acc[ct] = __builtin_amdgcn_mfma_f32_16x16x32_bf16(al1, bh1, acc[ct], 0, 0, 0);
  }

  // ---- phase 1.5: redistribute to selection layout ----
  // wave w owns rows {w, w+4, w+8, w+12}; key[rr][j] <-> col j*64+lane
  unsigned key[4][NJ];
  const int r0 = (lane >> 4) * 4;
  #pragma unroll
  for (int c = 0; c < 4; ++c) {
    if (w == c) {
      #pragma unroll
      for (int ct = 0; ct < 32; ++ct) {
        const int col = ct * 16 + fr;
        #pragma unroll
        for (int j = 0; j < 4; ++j)
          Sb[r0 + j][col] = acc[ct][j] * 0.125f;   // exact pow-2 scale
      }
    }
    __syncthreads();
    #pragma unroll
    for (int rr = 0; rr < 4; ++rr) {
      const int row = w + rr * 4;
      #pragma unroll
      for (int jj = 0; jj < 8; ++jj)
        key[rr][c * 8 + jj] = fkey(Sb[row][jj * 64 + lane]);
    }
    __syncthreads();
  }

  int topk = *topk_p;
  if (topk > N_) topk = N_;
  const float* Vb = vm + (size_t)bb * N_ * D_ + hh * HD_;

  // ---- phases 2+3 per owned row ----
  #pragma unroll
  for (int rr = 0; rr < 4; ++rr) {
    // row max
    unsigned kmax = 0;
    #pragma unroll
    for (int j = 0; j < NJ; ++j) kmax = (key[rr][j] > kmax) ? key[rr][j] : kmax;
    #pragma unroll
    for (int o = 32; o; o >>= 1) {
      unsigned t = __shfl_xor(kmax, o);
      kmax = (t > kmax) ? t : kmax;
    }
    const float smax = fval(kmax);

    // exact kth-largest threshold (radix on keys, early exit at c==topk)
    unsigned thr = 0u;
    if (topk < N_) {
      for (int bit = 31; bit >= 0; --bit) {
        const unsigned cand = thr | (1u << bit);
        int c = 0;
        #pragma unroll
        for (int j = 0; j < NJ; ++j)
          c += __popcll(__ballot(key[rr][j] >= cand));
        if (c >= topk) {
          thr = cand;
          if (c == topk) break;   // selection set already exact
        }
      }
    }

    // compaction: store (idx, raw score)
    int base = 0;
    #pragma unroll
    for (int j = 0; j < NJ; ++j) {
      const bool sel = key[rr][j] >= thr;
      const unsigned long long m = __ballot(sel);
      if (sel) {
        const int pos = base + (int)__popcll(m & ((1ull << lane) - 1ull));
        if (pos < 128) {
          selIdx[w][pos] = j * 64 + lane;
          selS[w][pos]   = fval(key[rr][j]);
        }
      }
      base += (int)__popcll(m);
    }
    const int cnt = (base > 128) ? 128 : base;

    // deferred expf: 2 per lane max, then wave-reduce wsum
    float wsum = 0.f;
    if (lane < cnt) {
      float e = expf(selS[w][lane] - smax);
      selS[w][lane] = e; wsum += e;
    }
    if (lane + 64 < cnt) {
      float e = expf(selS[w][lane + 64] - smax);
      selS[w][lane + 64] = e; wsum += e;
    }
    #pragma unroll
    for (int o = 32; o; o >>= 1) wsum += __shfl_xor(wsum, o);

    // batched parallel V gather (lane = d)
    float outv = 0.f;
    int i = 0;
    for (; i + 16 <= cnt; i += 16) {
      int ix[16]; float wv[16], vv[16];
      #pragma unroll
      for (int t = 0; t < 16; ++t) {
        ix[t] = selIdx[w][i + t];
        wv[t] = selS[w][i + t];
      }
      #pragma unroll
      for (int t = 0; t < 16; ++t) vv[t] = Vb[(size_t)ix[t] * D_ + lane];
      #pragma unroll
      for (int t = 0; t < 16; ++t) outv += wv[t] * vv[t];
    }
    for (; i < cnt; ++i)
      outv += selS[w][i] * Vb[(size_t)selIdx[w][i] * D_ + lane];

    const float o = outv / wsum;
    const size_t oidx = ((size_t)bb * N_ + q0 + w + rr * 4) * D_ + hh * HD_ + lane;
    unsigned short hsh = bf16r(o);
    aoh[oidx] = hsh; aol[oidx] = bf16r(o - bf2f(hsh));
  }
}

// ---------------------------------------------------------------------------
// Orchestration. ws extent = 100 MB. Lifetime aliasing as R4, except q/k are
// now bf16 pairs (same [52,84) region; v f32 at [84,100)).
// ---------------------------------------------------------------------------
extern "C" void kernel_launch(void* const* d_in, const int* in_sizes, int n_in,
                              void* d_out, int out_size, void* d_ws, size_t ws_size,
                              hipStream_t stream) {
  const float* x      = (const float*)d_in[0];
  const float* ln1_g  = (const float*)d_in[1];
  const float* ln1_b  = (const float*)d_in[2];
  const float* w_in   = (const float*)d_in[3];
  const float* b_in   = (const float*)d_in[4];
  const float* wq     = (const float*)d_in[5];
  const float* wk     = (const float*)d_in[6];
  const float* wv     = (const float*)d_in[7];
  const float* wo     = (const float*)d_in[8];
  const float* bo     = (const float*)d_in[9];
  const float* ln2_g  = (const float*)d_in[10];
  const float* ln2_b  = (const float*)d_in[11];
  const float* w_up   = (const float*)d_in[12];
  const float* b_up   = (const float*)d_in[13];
  const float* w_gate = (const float*)d_in[14];
  const float* b_gate = (const float*)d_in[15];
  const float* w_down = (const float*)d_in[16];
  const float* b_down = (const float*)d_in[17];
  const int*   topk   = (const int*)d_in[18];
  float* out = (float*)d_out;

  char* p = (char*)d_ws;
  const size_t MB = 1024 * 1024;
  unsigned short* Wi_h = (unsigned short*)(p + 0 * MB);
  unsigned short* Wi_l = (unsigned short*)(p + 2 * MB);
  unsigned short* Wq_h = (unsigned short*)(p + 4 * MB);
  unsigned short* Wq_l = (unsigned short*)(p + 6 * MB);
  unsigned short* Wk_h = (unsigned short*)(p + 8 * MB);
  unsigned short* Wk_l = (unsigned short*)(p + 10 * MB);
  unsigned short* Wv_h = (unsigned short*)(p + 12 * MB);
  unsigned short* Wv_l = (unsigned short*)(p + 14 * MB);
  unsigned short* Wo_h = (unsigned short*)(p + 16 * MB);
  unsigned short* Wo_l = (unsigned short*)(p + 18 * MB);
  unsigned short* Wd0_h = (unsigned short*)(p + 20 * MB);
  unsigned short* Wd0_l = (unsigned short*)(p + 24 * MB);
  unsigned short* Wd1_h = (unsigned short*)(p + 28 * MB);
  unsigned short* Wd1_l = (unsigned short*)(p + 32 * MB);
  unsigned short* hp_h = (unsigned short*)(p + 36 * MB);
  unsigned short* hp_l = (unsigned short*)(p + 44 * MB);
  unsigned short* ff_h = (unsigned short*)(p + 36 * MB);
  unsigned short* ff_l = (unsigned short*)(p + 44 * MB);
  unsigned short* xn_h = (unsigned short*)(p + 52 * MB);
  unsigned short* xn_l = (unsigned short*)(p + 60 * MB);
  // q/k bf16 pairs + v f32 (attention inputs)
  unsigned short* q_h  = (unsigned short*)(p + 52 * MB);
  unsigned short* q_l  = (unsigned short*)(p + 60 * MB);
  unsigned short* k_h  = (unsigned short*)(p + 68 * MB);
  unsigned short* k_l  = (unsigned short*)(p + 76 * MB);
  float*          vb   = (float*)(p + 84 * MB);
  unsigned short* Wg_h = (unsigned short*)(p + 52 * MB);
  unsigned short* Wg_l = (unsigned short*)(p + 60 * MB);
  unsigned short* Wu_h = (unsigned short*)(p + 68 * MB);
  unsigned short* Wu_l = (unsigned short*)(p + 76 * MB);
  unsigned short* f1_h = (unsigned short*)(p + 84 * MB);
  unsigned short* ao_h = (unsigned short*)(p + 0 * MB);
  unsigned short* ao_l = (unsigned short*)(p + 8 * MB);
  unsigned short* f1_l = (unsigned short*)(p + 0 * MB);

  const dim3 blk(256);
  const dim3 gW1k(32, 32);
  const dim3 gWgu(128, 32);
  const dim3 gWd(32, 64);
  const dim3 g1024(16, 32);
  const dim3 g2048(32, 32);

  wconv_kernel<<<gW1k, blk, 0, stream>>>(w_in, Wi_h, Wi_l, 1024, 1024);
  wconv_kernel<<<gW1k, blk, 0, stream>>>(wq, Wq_h, Wq_l, 1024, 1024);
  wconv_kernel<<<gW1k, blk, 0, stream>>>(wk, Wk_h, Wk_l, 1024, 1024);
  wconv_kernel<<<gW1k, blk, 0, stream>>>(wv, Wv_h, Wv_l, 1024, 1024);
  wconv_kernel<<<gW1k, blk, 0, stream>>>(wo, Wo_h, Wo_l, 1024, 1024);
  wconv_kernel<<<gWd, blk, 0, stream>>>(w_down,               Wd0_h, Wd0_l, 2048, 1024);
  wconv_kernel<<<gWd, blk, 0, stream>>>(w_down + 2048 * 1024, Wd1_h, Wd1_l, 2048, 1024);

  ln_kernel<<<M_, blk, 0, stream>>>(x, ln1_g, ln1_b, xn_h, xn_l);
  gemm_sb<GO_PAIR_BIAS><<<g1024, blk, 0, stream>>>(xn_h, xn_l, Wi_h, Wi_l, b_in,
      nullptr, nullptr, nullptr, hp_h, hp_l, nullptr, M_, 1024, 1024);
  gemm_sb<GO_PAIR_NB><<<g1024, blk, 0, stream>>>(hp_h, hp_l, Wq_h, Wq_l, nullptr,
      nullptr, nullptr, nullptr, q_h, q_l, nullptr, M_, 1024, 1024);
  gemm_sb<GO_PAIR_NB><<<g1024, blk, 0, stream>>>(hp_h, hp_l, Wk_h, Wk_l, nullptr,
      nullptr, nullptr, nullptr, k_h, k_l, nullptr, M_, 1024, 1024);
  gemm_sb<GO_F32><<<g1024, blk, 0, stream>>>(hp_h, hp_l, Wv_h, Wv_l, nullptr,
      nullptr, nullptr, nullptr, nullptr, nullptr, vb, M_, 1024, 1024);

  attn_kernel<<<B_ * H_ * (N_ / 16), blk, 0, stream>>>(q_h, q_l, k_h, k_l, vb,
      ao_h, ao_l, topk);

  wconv_kernel<<<gWgu, blk, 0, stream>>>(w_gate, Wg_h, Wg_l, 1024, 4096);
  wconv_kernel<<<gWgu, blk, 0, stream>>>(w_up,   Wu_h, Wu_l, 1024, 4096);

  gemm_sb<GO_F32_BIAS_RESPAIR><<<g1024, blk, 0, stream>>>(ao_h, ao_l, Wo_h, Wo_l, bo,
      hp_h, hp_l, nullptr, nullptr, nullptr, out, M_, 1024, 1024);

  ln_kernel<<<M_, blk, 0, stream>>>(out, ln2_g, ln2_b, ff_h, ff_l);

  gemm_gateup<<<g2048, blk, 0, stream>>>(ff_h, ff_l,
      Wg_h, Wg_l, Wu_h, Wu_l, b_gate, b_up, f1_h, f1_l, M_, 2048, 1024);
  gemm_sb<GO_F32_BIAS_RESF32><<<g1024, blk, 0, stream>>>(f1_h, f1_l, Wd0_h, Wd0_l,
      b_down, nullptr, nullptr, out, nullptr, nullptr, out, M_, 1024, 2048);
  gemm_gateup<<<g2048, blk, 0, stream>>>(ff_h, ff_l,
      Wg_h + (size_t)2048 * 1024, Wg_l + (size_t)2048 * 1024,
      Wu_h + (size_t)2048 * 1024, Wu_l + (size_t)2048 * 1024,
      b_gate + 2048, b_up + 2048, f1_h, f1_l, M_, 2048, 1024);
  gemm_sb<GO_F32_RES_NB><<<g1024, blk, 0, stream>>>(f1_h, f1_l, Wd1_h, Wd1_l,
      nullptr, nullptr, nullptr, out, nullptr, nullptr, out, M_, 1024, 2048);
}

// Round 8
// 1312.632 us; speedup vs baseline: 2.6429x; 1.0158x over previous
//
#include <hip/hip_runtime.h>
#include <cstdint>

// ============================================================================
// ScaledCorticalColumn — R8: fix attn register spill found in R7.
// Phase 1 is now chunk-cooperative: 4 chunks x (each wave computes 16x128 via
// acc[8], all waves write Sb, sync, read keys). Peak live regs ~200 (was ~280
// -> spill at VGPR_Count=120). GEMM/LN/wconv stack unchanged from R4/R7.
// ============================================================================

#define DEV __device__ __forceinline__

constexpr int B_  = 2;
constexpr int N_  = 2048;
constexpr int D_  = 1024;
constexpr int H_  = 16;
constexpr int HD_ = 64;
constexpr int M_  = B_ * N_;          // 4096 rows
constexpr float EPS_ = 1e-5f;

using short8 = __attribute__((ext_vector_type(8))) short;
using f32x4  = __attribute__((ext_vector_type(4))) float;

DEV float4 ld4(const float* p) { return *reinterpret_cast<const float4*>(p); }
DEV void   st4(float* p, float4 v) { *reinterpret_cast<float4*>(p) = v; }

// bf16 round-to-nearest-even split helpers
DEV unsigned short bf16r(float x) {
  unsigned u = __float_as_uint(x);
  u += 0x7fffu + ((u >> 16) & 1u);
  return (unsigned short)(u >> 16);
}
DEV float bf2f(unsigned short h) { return __uint_as_float(((unsigned)h) << 16); }

// order-preserving float<->uint key map (monotone bijection, tie-exact)
DEV unsigned fkey(float f) {
  unsigned u = __float_as_uint(f);
  return u ^ ((unsigned)((int)u >> 31) | 0x80000000u);
}
DEV float fval(unsigned k) {
  unsigned u = (k & 0x80000000u) ? (k ^ 0x80000000u) : ~k;
  return __uint_as_float(u);
}

// ---------------------------------------------------------------------------
// Weight transpose-convert: W f32 [K][N] -> Thi/Tlo bf16 [N][K]. 32x32 tiles.
// ---------------------------------------------------------------------------
__global__ __launch_bounds__(256) void wconv_kernel(const float* __restrict__ W,
                                                    unsigned short* __restrict__ Thi,
                                                    unsigned short* __restrict__ Tlo,
                                                    int K, int N) {
  __shared__ float t[32][33];
  const int k0 = blockIdx.y * 32, n0 = blockIdx.x * 32;
  const int tid = threadIdx.x;
  const int r = tid >> 3, c4 = (tid & 7) * 4;
  float4 v = ld4(W + (size_t)(k0 + r) * N + n0 + c4);
  t[r][c4 + 0] = v.x; t[r][c4 + 1] = v.y; t[r][c4 + 2] = v.z; t[r][c4 + 3] = v.w;
  __syncthreads();
  const int n = tid >> 3, kc = (tid & 7) * 4;
  ushort4 hv, lv;
  {
    float x0 = t[kc + 0][n], x1 = t[kc + 1][n], x2 = t[kc + 2][n], x3 = t[kc + 3][n];
    hv.x = bf16r(x0); lv.x = bf16r(x0 - bf2f(hv.x));
    hv.y = bf16r(x1); lv.y = bf16r(x1 - bf2f(hv.y));
    hv.z = bf16r(x2); lv.z = bf16r(x2 - bf2f(hv.z));
    hv.w = bf16r(x3); lv.w = bf16r(x3 - bf2f(hv.w));
  }
  *reinterpret_cast<ushort4*>(&Thi[(size_t)(n0 + n) * K + k0 + kc]) = hv;
  *reinterpret_cast<ushort4*>(&Tlo[(size_t)(n0 + n) * K + k0 + kc]) = lv;
}

// ---------------------------------------------------------------------------
// LayerNorm: one block per row; writes bf16 hi/lo pair planes.
// ---------------------------------------------------------------------------
__global__ __launch_bounds__(256) void ln_kernel(const float* __restrict__ in,
                                                 const float* __restrict__ g,
                                                 const float* __restrict__ b,
                                                 unsigned short* __restrict__ ohi,
                                                 unsigned short* __restrict__ olo) {
  const int row = blockIdx.x;
  const int t = threadIdx.x;
  float4 v = ld4(in + (size_t)row * D_ + t * 4);
  float s  = v.x + v.y + v.z + v.w;
  float ss = v.x * v.x + v.y * v.y + v.z * v.z + v.w * v.w;
  #pragma unroll
  for (int o = 32; o; o >>= 1) { s += __shfl_down(s, o); ss += __shfl_down(ss, o); }
  __shared__ float rs[4], rss[4];
  const int wid = t >> 6, lane = t & 63;
  if (lane == 0) { rs[wid] = s; rss[wid] = ss; }
  __syncthreads();
  s  = rs[0] + rs[1] + rs[2] + rs[3];
  ss = rss[0] + rss[1] + rss[2] + rss[3];
  const float mean = s * (1.f / D_);
  const float var  = ss * (1.f / D_) - mean * mean;
  const float rstd = rsqrtf(var + EPS_);
  float4 gv = ld4(g + t * 4);
  float4 bv = ld4(b + t * 4);
  float o0 = (v.x - mean) * rstd * gv.x + bv.x;
  float o1 = (v.y - mean) * rstd * gv.y + bv.y;
  float o2 = (v.z - mean) * rstd * gv.z + bv.z;
  float o3 = (v.w - mean) * rstd * gv.w + bv.w;
  ushort4 hv, lv;
  hv.x = bf16r(o0); lv.x = bf16r(o0 - bf2f(hv.x));
  hv.y = bf16r(o1); lv.y = bf16r(o1 - bf2f(hv.y));
  hv.z = bf16r(o2); lv.z = bf16r(o2 - bf2f(hv.z));
  hv.w = bf16r(o3); lv.w = bf16r(o3 - bf2f(hv.w));
  *reinterpret_cast<ushort4*>(&ohi[(size_t)row * D_ + t * 4]) = hv;
  *reinterpret_cast<ushort4*>(&olo[(size_t)row * D_ + t * 4]) = lv;
}

// ---------------------------------------------------------------------------
// Split-bf16 GEMM (unchanged from R7)
// ---------------------------------------------------------------------------
enum { GO_PAIR_BIAS = 0, GO_F32 = 1, GO_F32_BIAS_RESPAIR = 2,
       GO_F32_BIAS_RESF32 = 3, GO_F32_RES_NB = 4, GO_PAIR_NB = 5 };

template <int EPI>
__global__ __launch_bounds__(256) void gemm_sb(const unsigned short* __restrict__ Ah,
                                               const unsigned short* __restrict__ Al,
                                               const unsigned short* __restrict__ Bh,
                                               const unsigned short* __restrict__ Bl,
                                               const float* __restrict__ bias,
                                               const unsigned short* __restrict__ Rh,
                                               const unsigned short* __restrict__ Rl,
                                               const float* __restrict__ Rf,
                                               unsigned short* __restrict__ Ohi,
                                               unsigned short* __restrict__ Olo,
                                               float* __restrict__ Of,
                                               int M, int N, int K) {
  __shared__ unsigned short Ahs[128 * 40], Als[128 * 40];
  __shared__ unsigned short Bhs[64 * 40],  Bls[64 * 40];
  const int tid = threadIdx.x;
  const int m0 = blockIdx.y * 128, n0 = blockIdx.x * 64;
  const int lane = tid & 63, w = tid >> 6;
  const int wr = w >> 1, wc = w & 1;

  const int rA0 = tid >> 2, rA1 = 64 + (tid >> 2), chA = (tid & 3) * 8;
  const int rB = tid >> 2,  chB = (tid & 3) * 8;
  const size_t gA0 = (size_t)(m0 + rA0) * K + chA;
  const size_t gA1 = (size_t)(m0 + rA1) * K + chA;
  const size_t gB  = (size_t)(n0 + rB) * K + chB;
  const int lA0 = rA0 * 40 + chA, lA1 = rA1 * 40 + chA, lB = rB * 40 + chB;

  f32x4 acc[4][2];
  #pragma unroll
  for (int i = 0; i < 4; ++i)
    #pragma unroll
    for (int j = 0; j < 2; ++j) acc[i][j] = f32x4{0.f, 0.f, 0.f, 0.f};

  const int fr = lane & 15, fk = (lane >> 4) * 8;
  const int arow0 = (wr * 64 + fr) * 40 + fk;
  const int brow0 = (wc * 32 + fr) * 40 + fk;

  for (int k0 = 0; k0 < K; k0 += 32) {
    short8 a0h = *reinterpret_cast<const short8*>(&Ah[gA0 + k0]);
    short8 a1h = *reinterpret_cast<const short8*>(&Ah[gA1 + k0]);
    short8 a0l = *reinterpret_cast<const short8*>(&Al[gA0 + k0]);
    short8 a1l = *reinterpret_cast<const short8*>(&Al[gA1 + k0]);
    short8 bh  = *reinterpret_cast<const short8*>(&Bh[gB + k0]);
    short8 bl  = *reinterpret_cast<const short8*>(&Bl[gB + k0]);
    __syncthreads();
    *reinterpret_cast<short8*>(&Ahs[lA0]) = a0h;
    *reinterpret_cast<short8*>(&Ahs[lA1]) = a1h;
    *reinterpret_cast<short8*>(&Als[lA0]) = a0l;
    *reinterpret_cast<short8*>(&Als[lA1]) = a1l;
    *reinterpret_cast<short8*>(&Bhs[lB])  = bh;
    *reinterpret_cast<short8*>(&Bls[lB])  = bl;
    __syncthreads();

    short8 amh[4], aml[4], bnh[2], bnl[2];
    #pragma unroll
    for (int mf = 0; mf < 4; ++mf) {
      amh[mf] = *reinterpret_cast<const short8*>(&Ahs[arow0 + mf * 16 * 40]);
      aml[mf] = *reinterpret_cast<const short8*>(&Als[arow0 + mf * 16 * 40]);
    }
    #pragma unroll
    for (int nf = 0; nf < 2; ++nf) {
      bnh[nf] = *reinterpret_cast<const short8*>(&Bhs[brow0 + nf * 16 * 40]);
      bnl[nf] = *reinterpret_cast<const short8*>(&Bls[brow0 + nf * 16 * 40]);
    }
    #pragma unroll
    for (int mf = 0; mf < 4; ++mf)
      #pragma unroll
      for (int nf = 0; nf < 2; ++nf) {
        acc[mf][nf] = __builtin_amdgcn_mfma_f32_16x16x32_bf16(amh[mf], bnh[nf], acc[mf][nf], 0, 0, 0);
        acc[mf][nf] = __builtin_amdgcn_mfma_f32_16x16x32_bf16(amh[mf], bnl[nf], acc[mf][nf], 0, 0, 0);
        acc[mf][nf] = __builtin_amdgcn_mfma_f32_16x16x32_bf16(aml[mf], bnh[nf], acc[mf][nf], 0, 0, 0);
      }
  }

  const int er = (lane >> 4) * 4, ec = lane & 15;
  #pragma unroll
  for (int mf = 0; mf < 4; ++mf)
    #pragma unroll
    for (int nf = 0; nf < 2; ++nf)
      #pragma unroll
      for (int j = 0; j < 4; ++j) {
        const int m = m0 + wr * 64 + mf * 16 + er + j;
        const int n = n0 + wc * 32 + nf * 16 + ec;
        float v = acc[mf][nf][j];
        if constexpr (EPI == GO_PAIR_BIAS || EPI == GO_F32_BIAS_RESPAIR ||
                      EPI == GO_F32_BIAS_RESF32) v += bias[n];
        const size_t idx = (size_t)m * N + n;
        if constexpr (EPI == GO_PAIR_BIAS || EPI == GO_PAIR_NB) {
          unsigned short h = bf16r(v);
          Ohi[idx] = h; Olo[idx] = bf16r(v - bf2f(h));
        } else if constexpr (EPI == GO_F32) {
          Of[idx] = v;
        } else if constexpr (EPI == GO_F32_BIAS_RESPAIR) {
          Of[idx] = v + bf2f(Rh[idx]) + bf2f(Rl[idx]);
        } else {  // GO_F32_BIAS_RESF32 / GO_F32_RES_NB (Rf may alias Of)
          Of[idx] = v + Rf[idx];
        }
      }
}

// ---------------------------------------------------------------------------
// Dual GEMM (gate & up share A) — unchanged
// ---------------------------------------------------------------------------
__global__ __launch_bounds__(256) void gemm_gateup(const unsigned short* __restrict__ Ah,
                                                   const unsigned short* __restrict__ Al,
                                                   const unsigned short* __restrict__ Gh,
                                                   const unsigned short* __restrict__ Gl,
                                                   const unsigned short* __restrict__ Uh,
                                                   const unsigned short* __restrict__ Ul,
                                                   const float* __restrict__ bg,
                                                   const float* __restrict__ bu,
                                                   unsigned short* __restrict__ Ohi,
                                                   unsigned short* __restrict__ Olo,
                                                   int M, int N, int K) {
  __shared__ unsigned short Ahs[128 * 40], Als[128 * 40];
  __shared__ unsigned short Ghs[64 * 40], Gls[64 * 40], Uhs[64 * 40], Uls[64 * 40];
  const int tid = threadIdx.x;
  const int m0 = blockIdx.y * 128, n0 = blockIdx.x * 64;
  const int lane = tid & 63, w = tid >> 6;
  const int wr = w >> 1, wc = w & 1;

  const int rA0 = tid >> 2, rA1 = 64 + (tid >> 2), chA = (tid & 3) * 8;
  const int rB = tid >> 2, chB = (tid & 3) * 8;
  const size_t gA0 = (size_t)(m0 + rA0) * K + chA;
  const size_t gA1 = (size_t)(m0 + rA1) * K + chA;
  const size_t gB  = (size_t)(n0 + rB) * K + chB;
  const int lA0 = rA0 * 40 + chA, lA1 = rA1 * 40 + chA, lB = rB * 40 + chB;

  f32x4 accg[4][2], accu[4][2];
  #pragma unroll
  for (int i = 0; i < 4; ++i)
    #pragma unroll
    for (int j = 0; j < 2; ++j) {
      accg[i][j] = f32x4{0.f, 0.f, 0.f, 0.f};
      accu[i][j] = f32x4{0.f, 0.f, 0.f, 0.f};
    }

  const int fr = lane & 15, fk = (lane >> 4) * 8;
  const int arow0 = (wr * 64 + fr) * 40 + fk;
  const int brow0 = (wc * 32 + fr) * 40 + fk;

  for (int k0 = 0; k0 < K; k0 += 32) {
    short8 a0h = *reinterpret_cast<const short8*>(&Ah[gA0 + k0]);
    short8 a1h = *reinterpret_cast<const short8*>(&Ah[gA1 + k0]);
    short8 a0l = *reinterpret_cast<const short8*>(&Al[gA0 + k0]);
    short8 a1l = *reinterpret_cast<const short8*>(&Al[gA1 + k0]);
    short8 gh = *reinterpret_cast<const short8*>(&Gh[gB + k0]);
    short8 gl = *reinterpret_cast<const short8*>(&Gl[gB + k0]);
    short8 uh = *reinterpret_cast<const short8*>(&Uh[gB + k0]);
    short8 ul = *reinterpret_cast<const short8*>(&Ul[gB + k0]);
    __syncthreads();
    *reinterpret_cast<short8*>(&Ahs[lA0]) = a0h;
    *reinterpret_cast<short8*>(&Ahs[lA1]) = a1h;
    *reinterpret_cast<short8*>(&Als[lA0]) = a0l;
    *reinterpret_cast<short8*>(&Als[lA1]) = a1l;
    *reinterpret_cast<short8*>(&Ghs[lB]) = gh;
    *reinterpret_cast<short8*>(&Gls[lB]) = gl;
    *reinterpret_cast<short8*>(&Uhs[lB]) = uh;
    *reinterpret_cast<short8*>(&Uls[lB]) = ul;
    __syncthreads();

    short8 amh[4], aml[4];
    #pragma unroll
    for (int mf = 0; mf < 4; ++mf) {
      amh[mf] = *reinterpret_cast<const short8*>(&Ahs[arow0 + mf * 16 * 40]);
      aml[mf] = *reinterpret_cast<const short8*>(&Als[arow0 + mf * 16 * 40]);
    }
    #pragma unroll
    for (int nf = 0; nf < 2; ++nf) {
      short8 gnh = *reinterpret_cast<const short8*>(&Ghs[brow0 + nf * 16 * 40]);
      short8 gnl = *reinterpret_cast<const short8*>(&Gls[brow0 + nf * 16 * 40]);
      short8 unh = *reinterpret_cast<const short8*>(&Uhs[brow0 + nf * 16 * 40]);
      short8 unl = *reinterpret_cast<const short8*>(&Uls[brow0 + nf * 16 * 40]);
      #pragma unroll
      for (int mf = 0; mf < 4; ++mf) {
        accg[mf][nf] = __builtin_amdgcn_mfma_f32_16x16x32_bf16(amh[mf], gnh, accg[mf][nf], 0, 0, 0);
        accg[mf][nf] = __builtin_amdgcn_mfma_f32_16x16x32_bf16(amh[mf], gnl, accg[mf][nf], 0, 0, 0);
        accg[mf][nf] = __builtin_amdgcn_mfma_f32_16x16x32_bf16(aml[mf], gnh, accg[mf][nf], 0, 0, 0);
        accu[mf][nf] = __builtin_amdgcn_mfma_f32_16x16x32_bf16(amh[mf], unh, accu[mf][nf], 0, 0, 0);
        accu[mf][nf] = __builtin_amdgcn_mfma_f32_16x16x32_bf16(amh[mf], unl, accu[mf][nf], 0, 0, 0);
        accu[mf][nf] = __builtin_amdgcn_mfma_f32_16x16x32_bf16(aml[mf], unh, accu[mf][nf], 0, 0, 0);
      }
    }
  }

  const int er = (lane >> 4) * 4, ec = lane & 15;
  #pragma unroll
  for (int mf = 0; mf < 4; ++mf)
    #pragma unroll
    for (int nf = 0; nf < 2; ++nf)
      #pragma unroll
      for (int j = 0; j < 4; ++j) {
        const int m = m0 + wr * 64 + mf * 16 + er + j;
        const int n = n0 + wc * 32 + nf * 16 + ec;
        float g = accg[mf][nf][j] + bg[n];
        float u = accu[mf][nf][j] + bu[n];
        float f = (g / (1.f + expf(-g))) * u;
        const size_t idx = (size_t)m * N + n;
        unsigned short h = bf16r(f);
        Ohi[idx] = h; Olo[idx] = bf16r(f - bf2f(h));
      }
}

// ---------------------------------------------------------------------------
// Sparse attention v4: QBLK=16 rows/block, 4 waves, chunk-cooperative.
//  For each of 4 column-chunks (512 cols):
//    - wave w computes 16x128 sub-block (cols chunk+w*128..+128) via acc[8]
//      (32 VGPRs live, not 128) with split-bf16 MFMA;
//    - all waves write Sb[16][513]; sync; each wave reads 8 keys/owned-row.
//  Then per-row: exact radix-select (early exit), compaction, deferred expf,
//  batched parallel V gather. Peak regs ~200 -> no spill (R7 had VGPR=120 +
//  scratch spill of the 280-reg live set).
// ---------------------------------------------------------------------------
__global__ __launch_bounds__(256, 2) void attn_kernel(
    const unsigned short* __restrict__ qh, const unsigned short* __restrict__ ql,
    const unsigned short* __restrict__ kh, const unsigned short* __restrict__ kl,
    const float* __restrict__ vm,
    unsigned short* __restrict__ aoh, unsigned short* __restrict__ aol,
    const int* __restrict__ topk_p) {
  constexpr int QB = 16;
  constexpr int NJ = N_ / 64;               // 32 keys/lane/row
  __shared__ float Sb[QB][513];             // 32.8 KB chunk strip
  __shared__ int   selIdx[4][128];
  __shared__ float selS[4][128];

  const int tid = threadIdx.x;
  const int lane = tid & 63, w = tid >> 6;
  // XCD-chunked bijective swizzle: 4096 = 8 XCDs x 512
  const int bid = ((blockIdx.x & 7) << 9) | (blockIdx.x >> 3);
  const int qt = bid & 127;
  const int hh = (bid >> 7) & (H_ - 1);
  const int bb = bid >> 11;
  const int q0 = qt * QB;

  const int fr = lane & 15;                 // frag row (A) / col (B)
  const int fk = (lane >> 4) * 8;           // frag k-offset (bf16 units)

  // Q fragments for the 16 block rows (each wave holds the same A-frag)
  const size_t qbase = ((size_t)(bb * N_ + q0 + fr)) * D_ + hh * HD_ + fk;
  short8 ah0 = *reinterpret_cast<const short8*>(qh + qbase);
  short8 ah1 = *reinterpret_cast<const short8*>(qh + qbase + 32);
  short8 al0 = *reinterpret_cast<const short8*>(ql + qbase);
  short8 al1 = *reinterpret_cast<const short8*>(ql + qbase + 32);

  unsigned key[4][NJ];                      // wave w owns rows {w,w+4,w+8,w+12}
  const int r0 = (lane >> 4) * 4;

  // ---- phase 1: 4 chunks of 512 cols, cooperative ----
  for (int cc = 0; cc < 4; ++cc) {
    // wave w covers within-chunk cols [w*128, w*128+128): 8 MFMA col-tiles
    const int colbase = cc * 512 + w * 128;
    const size_t kwb = ((size_t)(bb * N_ + colbase + fr)) * D_ + hh * HD_ + fk;

    f32x4 acc[8];
    #pragma unroll
    for (int ctl = 0; ctl < 8; ++ctl) acc[ctl] = f32x4{0.f, 0.f, 0.f, 0.f};
    #pragma unroll
    for (int ctl = 0; ctl < 8; ++ctl) {
      const size_t kb0 = kwb + (size_t)ctl * 16 * D_;
      short8 bh0 = *reinterpret_cast<const short8*>(kh + kb0);
      short8 bh1 = *reinterpret_cast<const short8*>(kh + kb0 + 32);
      short8 bl0 = *reinterpret_cast<const short8*>(kl + kb0);
      short8 bl1 = *reinterpret_cast<const short8*>(kl + kb0 + 32);
      acc[ctl] = __builtin_amdgcn_mfma_f32_16x16x32_bf16(ah0, bh0, acc[ctl], 0, 0, 0);
      acc[ctl] = __builtin_amdgcn_mfma_f32_16x16x32_bf16(ah0, bl0, acc[ctl], 0, 0, 0);
      acc[ctl] = __builtin_amdgcn_mfma_f32_16x16x32_bf16(al0, bh0, acc[ctl], 0, 0, 0);
      acc[ctl] = __builtin_amdgcn_mfma_f32_16x16x32_bf16(ah1, bh1, acc[ctl], 0, 0, 0);
      acc[ctl] = __builtin_amdgcn_mfma_f32_16x16x32_bf16(ah1, bl1, acc[ctl], 0, 0, 0);
      acc[ctl] = __builtin_amdgcn_mfma_f32_16x16x32_bf16(al1, bh1, acc[ctl], 0, 0, 0);
    }

    __syncthreads();                        // prev chunk's Sb reads complete
    #pragma unroll
    for (int ctl = 0; ctl < 8; ++ctl) {
      const int col = w * 128 + ctl * 16 + fr;         // within-chunk col
      #pragma unroll
      for (int j = 0; j < 4; ++j)
        Sb[r0 + j][col] = acc[ctl][j] * 0.125f;        // exact pow-2 scale
    }
    __syncthreads();

    #pragma unroll
    for (int rr = 0; rr < 4; ++rr) {
      const int row = w + rr * 4;
      #pragma unroll
      for (int jj = 0; jj < 8; ++jj)
        key[rr][cc * 8 + jj] = fkey(Sb[row][jj * 64 + lane]);
    }
  }

  int topk = *topk_p;
  if (topk > N_) topk = N_;
  const float* Vb = vm + (size_t)bb * N_ * D_ + hh * HD_;

  // ---- phases 2+3 per owned row ----
  #pragma unroll
  for (int rr = 0; rr < 4; ++rr) {
    // row max
    unsigned kmax = 0;
    #pragma unroll
    for (int j = 0; j < NJ; ++j) kmax = (key[rr][j] > kmax) ? key[rr][j] : kmax;
    #pragma unroll
    for (int o = 32; o; o >>= 1) {
      unsigned t = __shfl_xor(kmax, o);
      kmax = (t > kmax) ? t : kmax;
    }
    const float smax = fval(kmax);

    // exact kth-largest threshold (radix on keys, early exit at c==topk)
    unsigned thr = 0u;
    if (topk < N_) {
      for (int bit = 31; bit >= 0; --bit) {
        const unsigned cand = thr | (1u << bit);
        int c = 0;
        #pragma unroll
        for (int j = 0; j < NJ; ++j)
          c += __popcll(__ballot(key[rr][j] >= cand));
        if (c >= topk) {
          thr = cand;
          if (c == topk) break;   // selection set already exact
        }
      }
    }

    // compaction: store (idx, raw score)
    int base = 0;
    #pragma unroll
    for (int j = 0; j < NJ; ++j) {
      const bool sel = key[rr][j] >= thr;
      const unsigned long long m = __ballot(sel);
      if (sel) {
        const int pos = base + (int)__popcll(m & ((1ull << lane) - 1ull));
        if (pos < 128) {
          selIdx[w][pos] = j * 64 + lane;
          selS[w][pos]   = fval(key[rr][j]);
        }
      }
      base += (int)__popcll(m);
    }
    const int cnt = (base > 128) ? 128 : base;

    // deferred expf: 2 per lane max, then wave-reduce wsum
    float wsum = 0.f;
    if (lane < cnt) {
      float e = expf(selS[w][lane] - smax);
      selS[w][lane] = e; wsum += e;
    }
    if (lane + 64 < cnt) {
      float e = expf(selS[w][lane + 64] - smax);
      selS[w][lane + 64] = e; wsum += e;
    }
    #pragma unroll
    for (int o = 32; o; o >>= 1) wsum += __shfl_xor(wsum, o);

    // batched parallel V gather (lane = d)
    float outv = 0.f;
    int i = 0;
    for (; i + 16 <= cnt; i += 16) {
      int ix[16]; float wv[16], vv[16];
      #pragma unroll
      for (int t = 0; t < 16; ++t) {
        ix[t] = selIdx[w][i + t];
        wv[t] = selS[w][i + t];
      }
      #pragma unroll
      for (int t = 0; t < 16; ++t) vv[t] = Vb[(size_t)ix[t] * D_ + lane];
      #pragma unroll
      for (int t = 0; t < 16; ++t) outv += wv[t] * vv[t];
    }
    for (; i < cnt; ++i)
      outv += selS[w][i] * Vb[(size_t)selIdx[w][i] * D_ + lane];

    const float o = outv / wsum;
    const size_t oidx = ((size_t)bb * N_ + q0 + w + rr * 4) * D_ + hh * HD_ + lane;
    unsigned short hsh = bf16r(o);
    aoh[oidx] = hsh; aol[oidx] = bf16r(o - bf2f(hsh));
  }
}

// ---------------------------------------------------------------------------
// Orchestration. ws extent = 100 MB, lifetime aliasing unchanged from R7.
// ---------------------------------------------------------------------------
extern "C" void kernel_launch(void* const* d_in, const int* in_sizes, int n_in,
                              void* d_out, int out_size, void* d_ws, size_t ws_size,
                              hipStream_t stream) {
  const float* x      = (const float*)d_in[0];
  const float* ln1_g  = (const float*)d_in[1];
  const float* ln1_b  = (const float*)d_in[2];
  const float* w_in   = (const float*)d_in[3];
  const float* b_in   = (const float*)d_in[4];
  const float* wq     = (const float*)d_in[5];
  const float* wk     = (const float*)d_in[6];
  const float* wv     = (const float*)d_in[7];
  const float* wo     = (const float*)d_in[8];
  const float* bo     = (const float*)d_in[9];
  const float* ln2_g  = (const float*)d_in[10];
  const float* ln2_b  = (const float*)d_in[11];
  const float* w_up   = (const float*)d_in[12];
  const float* b_up   = (const float*)d_in[13];
  const float* w_gate = (const float*)d_in[14];
  const float* b_gate = (const float*)d_in[15];
  const float* w_down = (const float*)d_in[16];
  const float* b_down = (const float*)d_in[17];
  const int*   topk   = (const int*)d_in[18];
  float* out = (float*)d_out;

  char* p = (char*)d_ws;
  const size_t MB = 1024 * 1024;
  unsigned short* Wi_h = (unsigned short*)(p + 0 * MB);
  unsigned short* Wi_l = (unsigned short*)(p + 2 * MB);
  unsigned short* Wq_h = (unsigned short*)(p + 4 * MB);
  unsigned short* Wq_l = (unsigned short*)(p + 6 * MB);
  unsigned short* Wk_h = (unsigned short*)(p + 8 * MB);
  unsigned short* Wk_l = (unsigned short*)(p + 10 * MB);
  unsigned short* Wv_h = (unsigned short*)(p + 12 * MB);
  unsigned short* Wv_l = (unsigned short*)(p + 14 * MB);
  unsigned short* Wo_h = (unsigned short*)(p + 16 * MB);
  unsigned short* Wo_l = (unsigned short*)(p + 18 * MB);
  unsigned short* Wd0_h = (unsigned short*)(p + 20 * MB);
  unsigned short* Wd0_l = (unsigned short*)(p + 24 * MB);
  unsigned short* Wd1_h = (unsigned short*)(p + 28 * MB);
  unsigned short* Wd1_l = (unsigned short*)(p + 32 * MB);
  unsigned short* hp_h = (unsigned short*)(p + 36 * MB);
  unsigned short* hp_l = (unsigned short*)(p + 44 * MB);
  unsigned short* ff_h = (unsigned short*)(p + 36 * MB);
  unsigned short* ff_l = (unsigned short*)(p + 44 * MB);
  unsigned short* xn_h = (unsigned short*)(p + 52 * MB);
  unsigned short* xn_l = (unsigned short*)(p + 60 * MB);
  unsigned short* q_h  = (unsigned short*)(p + 52 * MB);
  unsigned short* q_l  = (unsigned short*)(p + 60 * MB);
  unsigned short* k_h  = (unsigned short*)(p + 68 * MB);
  unsigned short* k_l  = (unsigned short*)(p + 76 * MB);
  float*          vb   = (float*)(p + 84 * MB);
  unsigned short* Wg_h = (unsigned short*)(p + 52 * MB);
  unsigned short* Wg_l = (unsigned short*)(p + 60 * MB);
  unsigned short* Wu_h = (unsigned short*)(p + 68 * MB);
  unsigned short* Wu_l = (unsigned short*)(p + 76 * MB);
  unsigned short* f1_h = (unsigned short*)(p + 84 * MB);
  unsigned short* ao_h = (unsigned short*)(p + 0 * MB);
  unsigned short* ao_l = (unsigned short*)(p + 8 * MB);
  unsigned short* f1_l = (unsigned short*)(p + 0 * MB);

  const dim3 blk(256);
  const dim3 gW1k(32, 32);
  const dim3 gWgu(128, 32);
  const dim3 gWd(32, 64);
  const dim3 g1024(16, 32);
  const dim3 g2048(32, 32);

  wconv_kernel<<<gW1k, blk, 0, stream>>>(w_in, Wi_h, Wi_l, 1024, 1024);
  wconv_kernel<<<gW1k, blk, 0, stream>>>(wq, Wq_h, Wq_l, 1024, 1024);
  wconv_kernel<<<gW1k, blk, 0, stream>>>(wk, Wk_h, Wk_l, 1024, 1024);
  wconv_kernel<<<gW1k, blk, 0, stream>>>(wv, Wv_h, Wv_l, 1024, 1024);
  wconv_kernel<<<gW1k, blk, 0, stream>>>(wo, Wo_h, Wo_l, 1024, 1024);
  wconv_kernel<<<gWd, blk, 0, stream>>>(w_down,               Wd0_h, Wd0_l, 2048, 1024);
  wconv_kernel<<<gWd, blk, 0, stream>>>(w_down + 2048 * 1024, Wd1_h, Wd1_l, 2048, 1024);

  ln_kernel<<<M_, blk, 0, stream>>>(x, ln1_g, ln1_b, xn_h, xn_l);
  gemm_sb<GO_PAIR_BIAS><<<g1024, blk, 0, stream>>>(xn_h, xn_l, Wi_h, Wi_l, b_in,
      nullptr, nullptr, nullptr, hp_h, hp_l, nullptr, M_, 1024, 1024);
  gemm_sb<GO_PAIR_NB><<<g1024, blk, 0, stream>>>(hp_h, hp_l, Wq_h, Wq_l, nullptr,
      nullptr, nullptr, nullptr, q_h, q_l, nullptr, M_, 1024, 1024);
  gemm_sb<GO_PAIR_NB><<<g1024, blk, 0, stream>>>(hp_h, hp_l, Wk_h, Wk_l, nullptr,
      nullptr, nullptr, nullptr, k_h, k_l, nullptr, M_, 1024, 1024);
  gemm_sb<GO_F32><<<g1024, blk, 0, stream>>>(hp_h, hp_l, Wv_h, Wv_l, nullptr,
      nullptr, nullptr, nullptr, nullptr, nullptr, vb, M_, 1024, 1024);

  attn_kernel<<<B_ * H_ * (N_ / 16), blk, 0, stream>>>(q_h, q_l, k_h, k_l, vb,
      ao_h, ao_l, topk);

  wconv_kernel<<<gWgu, blk, 0, stream>>>(w_gate, Wg_h, Wg_l, 1024, 4096);
  wconv_kernel<<<gWgu, blk, 0, stream>>>(w_up,   Wu_h, Wu_l, 1024, 4096);

  gemm_sb<GO_F32_BIAS_RESPAIR><<<g1024, blk, 0, stream>>>(ao_h, ao_l, Wo_h, Wo_l, bo,
      hp_h, hp_l, nullptr, nullptr, nullptr, out, M_, 1024, 1024);

  ln_kernel<<<M_, blk, 0, stream>>>(out, ln2_g, ln2_b, ff_h, ff_l);

  gemm_gateup<<<g2048, blk, 0, stream>>>(ff_h, ff_l,
      Wg_h, Wg_l, Wu_h, Wu_l, b_gate, b_up, f1_h, f1_l, M_, 2048, 1024);
  gemm_sb<GO_F32_BIAS_RESF32><<<g1024, blk, 0, stream>>>(f1_h, f1_l, Wd0_h, Wd0_l,
      b_down, nullptr, nullptr, out, nullptr, nullptr, out, M_, 1024, 2048);
  gemm_gateup<<<g2048, blk, 0, stream>>>(ff_h, ff_l,
      Wg_h + (size_t)2048 * 1024, Wg_l + (size_t)2048 * 1024,
      Wu_h + (size_t)2048 * 1024, Wu_l + (size_t)2048 * 1024,
      b_gate + 2048, b_up + 2048, f1_h, f1_l, M_, 2048, 1024);
  gemm_sb<GO_F32_RES_NB><<<g1024, blk, 0, stream>>>(f1_h, f1_l, Wd1_h, Wd1_l,
      nullptr, nullptr, nullptr, out, nullptr, nullptr, out, M_, 1024, 2048);
}